// Round 1
// baseline (2715.118 us; speedup 1.0000x reference)
//
#include <hip/hip_runtime.h>
#include <math.h>

// ---------------- workspace offsets (bytes) ----------------
#define OFF_CENT   0x0        // int [2][2048]                     16 KB
#define OFF_XSP    0x20000    // float4 [2][2048] coords            64 KB
#define OFF_XS6    0x40000    // float [2][2048][6]                 96 KB
#define OFF_KNN    0x60000    // int [2][2048][64] max               1 MB
#define OFF_F      0x180000   // float [2*2048][512] max             8 MB
#define OFF_UV     0xA00000   // float [2*2048][1024] max           16 MB
#define OFF_G      0x1A00000  // float [2*2048][512] max             8 MB
#define OFF_WCAT   0x2200000  // float [256][1024] max               1 MB (+slack)
#define OFF_BCAT   0x2400000  // float [1024]
#define OFF_FUSED  0x2500000  // float [2][4096][1280]              42 MB  -> ws end 77 MB
#define OFF_T      0x180000   // reuse (post-encoder)  float [8192][512]
#define OFF_H1     0x1200000  // reuse                 float [8192][512]
#define OFF_T2     0x2200000  // reuse                 float [8192][512]

// ---------------- helpers ----------------
__device__ __forceinline__ unsigned fkey_flip(float f) {
  unsigned u = __float_as_uint(f);
  return u ^ ((u >> 31) ? 0xFFFFFFFFu : 0x80000000u);
}
__device__ __forceinline__ float fkey_unflip(unsigned k) {
  unsigned u = k ^ ((k >> 31) ? 0x80000000u : 0xFFFFFFFFu);
  return __uint_as_float(u);
}

// ---------------- FPS: one block per batch, sequential 2048 steps ----------------
__global__ __launch_bounds__(512) void fps_kernel(const float* __restrict__ x,
                                                  int* __restrict__ cent)
{
  int b = blockIdx.x, tid = threadIdx.x;
  __shared__ float LX[4096], LY[4096], LZ[4096];
  __shared__ unsigned long long slots[2][8];
  float px[8], py[8], pz[8], dist[8];
#pragma unroll
  for (int i = 0; i < 8; ++i) {
    int p = tid + 512 * i;
    const float* r = x + ((long)b * 4096 + p) * 6;
    px[i] = r[0]; py[i] = r[1]; pz[i] = r[2];
    LX[p] = px[i]; LY[p] = py[i]; LZ[p] = pz[i];
    dist[i] = 1e10f;
  }
  if (tid == 0) cent[b * 2048] = 0;
  __syncthreads();
  float cx = LX[0], cy = LY[0], cz = LZ[0];
  int wid = tid >> 6, lane = tid & 63;
  for (int j = 1; j < 2048; ++j) {
    float bv = -1.0f; int bidx = 0;
#pragma unroll
    for (int i = 0; i < 8; ++i) {
      // exact replica of sum((xyz-c)**2, -1): ((dx*dx+dy*dy)+dz*dz), no FMA
      float dx = __fsub_rn(px[i], cx);
      float dy = __fsub_rn(py[i], cy);
      float dz = __fsub_rn(pz[i], cz);
      float d  = __fadd_rn(__fadd_rn(__fmul_rn(dx,dx), __fmul_rn(dy,dy)), __fmul_rn(dz,dz));
      float nd = fminf(dist[i], d);
      dist[i] = nd;
      if (nd > bv) { bv = nd; bidx = tid + 512 * i; }   // strict > keeps lowest index (i ascending)
    }
    // key: max dist, tie -> lowest index
    unsigned long long key = ((unsigned long long)__float_as_uint(bv) << 32)
                           | (unsigned)(0xFFFFFFFFu - (unsigned)bidx);
#pragma unroll
    for (int m = 32; m; m >>= 1) {
      unsigned long long o = __shfl_xor(key, m, 64);
      if (o > key) key = o;
    }
    if (lane == 0) slots[j & 1][wid] = key;
    __syncthreads();
    unsigned long long best = slots[j & 1][0];
#pragma unroll
    for (int wv = 1; wv < 8; ++wv) {
      unsigned long long o = slots[j & 1][wv];
      if (o > best) best = o;
    }
    int idx = (int)(0xFFFFFFFFu - (unsigned)(best & 0xFFFFFFFFu));
    if (tid == 0) cent[b * 2048 + j] = idx;
    cx = LX[idx]; cy = LY[idx]; cz = LZ[idx];
  }
}

// ---------------- gather subsampled points ----------------
__global__ void gather_xs_kernel(const float* __restrict__ x, const int* __restrict__ cent,
                                 float* __restrict__ xs6, float4* __restrict__ xsp)
{
  int t = blockIdx.x * 256 + threadIdx.x;
  if (t >= 2 * 2048) return;
  int b = t >> 11;
  int p = cent[t];
  const float* src = x + ((long)b * 4096 + p) * 6;
  float* dst = xs6 + (long)t * 6;
#pragma unroll
  for (int c = 0; c < 6; ++c) dst[c] = src[c];
  xsp[t] = make_float4(src[0], src[1], src[2], 0.0f);
}

// ---------------- kNN: one wave per query ----------------
template<int S, int K>
__global__ __launch_bounds__(256) void knn_kernel(const float4* __restrict__ xsp,
                                                  int* __restrict__ out)
{
  constexpr int NI = S / 64;
  __shared__ float4 P[S];
  int b = (blockIdx.x * 4) / S;
  int wid = threadIdx.x >> 6, lane = threadIdx.x & 63;
  int s = (blockIdx.x * 4 + wid) & (S - 1);
  for (int i = threadIdx.x; i < S; i += 256) P[i] = xsp[b * 2048 + i];
  __syncthreads();
  float4 Q = P[s];
  float saq = __fadd_rn(__fadd_rn(__fmul_rn(Q.x,Q.x), __fmul_rn(Q.y,Q.y)), __fmul_rn(Q.z,Q.z));
  float dd[NI];
#pragma unroll
  for (int i = 0; i < NI; ++i) {
    float4 c = P[i * 64 + lane];
    float sac = __fadd_rn(__fadd_rn(__fmul_rn(c.x,c.x), __fmul_rn(c.y,c.y)), __fmul_rn(c.z,c.z));
    float dot = __fadd_rn(__fadd_rn(__fmul_rn(Q.x,c.x), __fmul_rn(Q.y,c.y)), __fmul_rn(Q.z,c.z));
    dd[i] = __fsub_rn(__fadd_rn(saq, sac), __fmul_rn(2.0f, dot));
  }
  long obase = ((long)b * S + s) * K;
  for (int t = 0; t < K; ++t) {
    float bv = INFINITY; int bi = 0;
#pragma unroll
    for (int i = 0; i < NI; ++i) if (dd[i] < bv) { bv = dd[i]; bi = i; }
    unsigned long long key = ((unsigned long long)fkey_flip(bv) << 32)
                           | (unsigned)(bi * 64 + lane);
#pragma unroll
    for (int m = 32; m; m >>= 1) {
      unsigned long long o = __shfl_xor(key, m, 64);
      if (o < key) key = o;
    }
    unsigned cand = (unsigned)key;
    if ((int)(cand & 63) == lane) {
      int slot = cand >> 6;
#pragma unroll
      for (int i = 0; i < NI; ++i) if (i == slot) dd[i] = INFINITY;
    }
    if (lane == 0) out[obase + t] = (int)cand;
  }
}

// ---------------- Wcat prep: [2C,C'] -> [C, 2C'] with (Wa-Wb | Wb), bias -> (b | 0) ----------------
__global__ void wcat_prep(const float* __restrict__ W, const float* __restrict__ bias,
                          int C, int Cp, float* __restrict__ Wcat, float* __restrict__ bcat)
{
  int n2 = 2 * Cp;
  int total = C * n2;
  for (int t = blockIdx.x * 256 + threadIdx.x; t < total + n2; t += gridDim.x * 256) {
    if (t < total) {
      int c = t / n2, n = t % n2;
      Wcat[t] = (n < Cp) ? (W[c * Cp + n] - W[(C + c) * Cp + n]) : W[(C + c) * Cp + (n - Cp)];
    } else {
      int n = t - total;
      bcat[n] = (n < Cp) ? bias[n] : 0.0f;
    }
  }
}

// ---------------- generic fp32 GEMM: C = A[M,K] * W[K,N] + bias ----------------
__global__ __launch_bounds__(256) void gemm_bias(
    const float* __restrict__ A, long strideA, int lda,
    const float* __restrict__ W, int N, int K,
    const float* __restrict__ bias,
    float* __restrict__ C, long strideC, int ldc)
{
  A += (long)blockIdx.z * strideA;
  C += (long)blockIdx.z * strideC;
  int rowBase = blockIdx.x * 64, colBase = blockIdx.y * 64;
  __shared__ float As[16][68];
  __shared__ float Ws[16][68];
  int tid = threadIdx.x;
  int tx = tid & 15, ty = tid >> 4;
  float acc[4][4] = {};
  for (int k0 = 0; k0 < K; k0 += 16) {
    {
      int r = tid >> 2, c0 = (tid & 3) * 4;
      const float* Ar = A + (long)(rowBase + r) * lda + k0 + c0;
#pragma unroll
      for (int u = 0; u < 4; ++u) {
        float val = 0.0f;
        if (k0 + c0 + u < K) val = Ar[u];
        As[c0 + u][r] = val;
      }
    }
    {
      int c = tid & 63, kr = tid >> 6;
#pragma unroll
      for (int u = 0; u < 4; ++u) {
        int kk = kr + u * 4;
        float val = 0.0f;
        if (k0 + kk < K) val = W[(long)(k0 + kk) * N + colBase + c];
        Ws[kk][c] = val;
      }
    }
    __syncthreads();
#pragma unroll
    for (int kk = 0; kk < 16; ++kk) {
      float4 av = *(const float4*)&As[kk][ty * 4];
      float4 wv = *(const float4*)&Ws[kk][tx * 4];
      float a_[4] = {av.x, av.y, av.z, av.w};
      float w_[4] = {wv.x, wv.y, wv.z, wv.w};
#pragma unroll
      for (int i = 0; i < 4; ++i)
#pragma unroll
        for (int j = 0; j < 4; ++j)
          acc[i][j] = fmaf(a_[i], w_[j], acc[i][j]);
    }
    __syncthreads();
  }
#pragma unroll
  for (int i = 0; i < 4; ++i) {
    int r = rowBase + ty * 4 + i;
    int c0 = colBase + tx * 4;
    float4 o;
    o.x = acc[i][0] + bias[c0 + 0];
    o.y = acc[i][1] + bias[c0 + 1];
    o.z = acc[i][2] + bias[c0 + 2];
    o.w = acc[i][3] + bias[c0 + 3];
    *(float4*)&C[(long)r * ldc + c0] = o;
  }
}

// ---------------- edge aggregation: F[s] = relu(u[s] + max_j v[nbr_j]) ----------------
__global__ void edge_agg(const float* __restrict__ UV, const int* __restrict__ idx,
                         int S, int k, int Cp, float* __restrict__ F)
{
  int bs = blockIdx.x;
  int b = bs / S;
  __shared__ int nb[64];
  if ((int)threadIdx.x < k) nb[threadIdx.x] = idx[(long)bs * k + threadIdx.x];
  __syncthreads();
  int ld = 2 * Cp;
  const float* Ub = UV + (long)bs * ld;
  for (int c = threadIdx.x; c < Cp; c += blockDim.x) {
    float m = -INFINITY;
    for (int j = 0; j < k; ++j) {
      float v = UV[(long)(b * S + nb[j]) * ld + Cp + c];
      m = fmaxf(m, v);
    }
    float r = Ub[c] + m;
    F[(long)bs * Cp + c] = r > 0.0f ? r : 0.0f;
  }
}

// ---------------- upsample: 3-NN inverse-distance interp, writes into fused concat ----------------
template<int S, int CP>
__global__ __launch_bounds__(256) void upsample_kernel(
    const float* __restrict__ x, const float4* __restrict__ xsp,
    const float* __restrict__ G, float* __restrict__ fused, int colOff)
{
  constexpr int NI = S / 64;
  __shared__ float4 P[S];
  int b = (blockIdx.x * 4) >> 12;
  int wid = threadIdx.x >> 6, lane = threadIdx.x & 63;
  int n = (blockIdx.x * 4 + wid) & 4095;
  for (int i = threadIdx.x; i < S; i += 256) P[i] = xsp[b * 2048 + i];
  __syncthreads();
  const float* q = x + ((long)b * 4096 + n) * 6;
  float qx = q[0], qy = q[1], qz = q[2];
  float saq = __fadd_rn(__fadd_rn(__fmul_rn(qx,qx), __fmul_rn(qy,qy)), __fmul_rn(qz,qz));
  float dd[NI];
#pragma unroll
  for (int i = 0; i < NI; ++i) {
    float4 c = P[i * 64 + lane];
    float sac = __fadd_rn(__fadd_rn(__fmul_rn(c.x,c.x), __fmul_rn(c.y,c.y)), __fmul_rn(c.z,c.z));
    float dot = __fadd_rn(__fadd_rn(__fmul_rn(qx,c.x), __fmul_rn(qy,c.y)), __fmul_rn(qz,c.z));
    dd[i] = __fsub_rn(__fadd_rn(saq, sac), __fmul_rn(2.0f, dot));
  }
  int id[3]; float w[3];
  for (int t = 0; t < 3; ++t) {
    float bv = INFINITY; int bi = 0;
#pragma unroll
    for (int i = 0; i < NI; ++i) if (dd[i] < bv) { bv = dd[i]; bi = i; }
    unsigned long long key = ((unsigned long long)fkey_flip(bv) << 32)
                           | (unsigned)(bi * 64 + lane);
#pragma unroll
    for (int m = 32; m; m >>= 1) {
      unsigned long long o = __shfl_xor(key, m, 64);
      if (o < key) key = o;
    }
    unsigned cand = (unsigned)key;
    float d2 = fkey_unflip((unsigned)(key >> 32));
    float d = __fsqrt_rn(fmaxf(d2, 0.0f));
    id[t] = (int)cand;
    w[t] = 1.0f / __fadd_rn(d, 1e-8f);
    if ((int)(cand & 63) == lane) {
      int slot = cand >> 6;
#pragma unroll
      for (int i = 0; i < NI; ++i) if (i == slot) dd[i] = INFINITY;
    }
  }
  float wsum = __fadd_rn(__fadd_rn(w[0], w[1]), w[2]);
  float w0 = w[0] / wsum, w1 = w[1] / wsum, w2 = w[2] / wsum;
  const float* g0 = G + (long)(b * S + id[0]) * CP;
  const float* g1 = G + (long)(b * S + id[1]) * CP;
  const float* g2 = G + (long)(b * S + id[2]) * CP;
  float* orow = fused + ((long)b * 4096 + n) * 1280 + colOff;
#pragma unroll
  for (int t = 0; t < CP / 64; ++t) {
    int c = lane + 64 * t;
    float v = __fadd_rn(__fadd_rn(__fmul_rn(w0, g0[c]), __fmul_rn(w1, g1[c])),
                        __fmul_rn(w2, g2[c]));
    orow[c] = v;
  }
}

// ---------------- GroupNorm(32,512) + relu (+ optional pos-enc), one group per thread ----------------
__global__ __launch_bounds__(256) void gn_kernel(const float* __restrict__ T,
    const float* __restrict__ gw, const float* __restrict__ gb,
    float* __restrict__ out, int addPos)
{
  int t = blockIdx.x * 256 + threadIdx.x;
  int row = t >> 5, g = t & 31;
  const float* p = T + (long)row * 512 + g * 16;
  float v[16];
#pragma unroll
  for (int i = 0; i < 4; ++i) {
    float4 f = *(const float4*)(p + i * 4);
    v[i*4+0] = f.x; v[i*4+1] = f.y; v[i*4+2] = f.z; v[i*4+3] = f.w;
  }
  float s = 0.0f;
#pragma unroll
  for (int i = 0; i < 16; ++i) s += v[i];
  float mu = s * 0.0625f;
  float var = 0.0f;
#pragma unroll
  for (int i = 0; i < 16; ++i) { float d = v[i] - mu; var += d * d; }
  var *= 0.0625f;
  float inv = 1.0f / sqrtf(var + 1e-5f);
  int cbase = g * 16;
  int n = row & 4095;
  float o[16];
#pragma unroll
  for (int i = 0; i < 16; ++i) {
    int c = cbase + i;
    float y = (v[i] - mu) * inv * gw[c] + gb[c];
    y = y > 0.0f ? y : 0.0f;
    if (addPos) {
      int half = c >> 1;
      float div = expf((float)(2 * half) * -0.017988946039016358f); // -ln(10000)/512
      float ang = (float)n * div;
      y += (c & 1) ? cosf(ang) : sinf(ang);
    }
    o[i] = y;
  }
  float* d = out + (long)row * 512 + cbase;
#pragma unroll
  for (int i = 0; i < 4; ++i) {
    float4 f; f.x = o[i*4+0]; f.y = o[i*4+1]; f.z = o[i*4+2]; f.w = o[i*4+3];
    *(float4*)(d + i * 4) = f;
  }
}

// ---------------- host-side launch helpers ----------------
static inline void launch_gemm(const float* A, long strideA, int lda,
                               const float* W, const float* bias,
                               float* C, long strideC, int ldc,
                               int Mb, int N, int K, int nb, hipStream_t s)
{
  dim3 grid(Mb / 64, N / 64, nb);
  gemm_bias<<<grid, 256, 0, s>>>(A, strideA, lda, W, N, K, bias, C, strideC, ldc);
}

extern "C" void kernel_launch(void* const* d_in, const int* in_sizes, int n_in,
                              void* d_out, int out_size, void* d_ws, size_t ws_size,
                              hipStream_t stream)
{
  const float* x     = (const float*)d_in[0];
  const float* e1_W0 = (const float*)d_in[1];  const float* e1_b0 = (const float*)d_in[2];
  const float* e1_W1 = (const float*)d_in[3];  const float* e1_b1 = (const float*)d_in[4];
  const float* e1_Wo = (const float*)d_in[5];  const float* e1_bo = (const float*)d_in[6];
  const float* e2_W0 = (const float*)d_in[7];  const float* e2_b0 = (const float*)d_in[8];
  const float* e2_W1 = (const float*)d_in[9];  const float* e2_b1 = (const float*)d_in[10];
  const float* e2_Wo = (const float*)d_in[11]; const float* e2_bo = (const float*)d_in[12];
  const float* e3_W0 = (const float*)d_in[13]; const float* e3_b0 = (const float*)d_in[14];
  const float* e3_W1 = (const float*)d_in[15]; const float* e3_b1 = (const float*)d_in[16];
  const float* e3_W2 = (const float*)d_in[17]; const float* e3_b2 = (const float*)d_in[18];
  const float* e3_Wo = (const float*)d_in[19]; const float* e3_bo = (const float*)d_in[20];
  const float* f_W1  = (const float*)d_in[21]; const float* f_b1  = (const float*)d_in[22];
  const float* g1_w  = (const float*)d_in[23]; const float* g1_b  = (const float*)d_in[24];
  const float* f_W2  = (const float*)d_in[25]; const float* f_b2  = (const float*)d_in[26];
  const float* g2_w  = (const float*)d_in[27]; const float* g2_b  = (const float*)d_in[28];

  char* ws = (char*)d_ws;
  int*    cent  = (int*)(ws + OFF_CENT);
  float4* xsp   = (float4*)(ws + OFF_XSP);
  float*  xs6   = (float*)(ws + OFF_XS6);
  int*    knn   = (int*)(ws + OFF_KNN);
  float*  F     = (float*)(ws + OFF_F);
  float*  UV    = (float*)(ws + OFF_UV);
  float*  G     = (float*)(ws + OFF_G);
  float*  WCAT  = (float*)(ws + OFF_WCAT);
  float*  BCAT  = (float*)(ws + OFF_BCAT);
  float*  FUSED = (float*)(ws + OFF_FUSED);
  float*  T     = (float*)(ws + OFF_T);
  float*  H1    = (float*)(ws + OFF_H1);
  float*  T2    = (float*)(ws + OFF_T2);

  fps_kernel<<<2, 512, 0, stream>>>(x, cent);
  gather_xs_kernel<<<16, 256, 0, stream>>>(x, cent, xs6, xsp);

  // ---- encoder 1: S=512, k=16, 6->128->256, proj 256 ----
  knn_kernel<512,16><<<256, 256, 0, stream>>>(xsp, knn);
  wcat_prep<<<256, 256, 0, stream>>>(e1_W0, e1_b0, 6, 128, WCAT, BCAT);
  launch_gemm(xs6, (long)2048*6, 6, WCAT, BCAT, UV, (long)512*256, 256, 512, 256, 6, 2, stream);
  edge_agg<<<dim3(2*512), 128, 0, stream>>>(UV, knn, 512, 16, 128, F);
  wcat_prep<<<256, 256, 0, stream>>>(e1_W1, e1_b1, 128, 256, WCAT, BCAT);
  launch_gemm(F, 0, 128, WCAT, BCAT, UV, 0, 512, 1024, 512, 128, 1, stream);
  edge_agg<<<dim3(2*512), 256, 0, stream>>>(UV, knn, 512, 16, 256, F);
  launch_gemm(F, 0, 256, e1_Wo, e1_bo, G, 0, 256, 1024, 256, 256, 1, stream);
  upsample_kernel<512,256><<<2048, 256, 0, stream>>>(x, xsp, G, FUSED, 0);

  // ---- encoder 2: S=1024, k=32, 6->256->512, proj 512 ----
  knn_kernel<1024,32><<<512, 256, 0, stream>>>(xsp, knn);
  wcat_prep<<<256, 256, 0, stream>>>(e2_W0, e2_b0, 6, 256, WCAT, BCAT);
  launch_gemm(xs6, (long)2048*6, 6, WCAT, BCAT, UV, (long)1024*512, 512, 1024, 512, 6, 2, stream);
  edge_agg<<<dim3(2*1024), 256, 0, stream>>>(UV, knn, 1024, 32, 256, F);
  wcat_prep<<<256, 256, 0, stream>>>(e2_W1, e2_b1, 256, 512, WCAT, BCAT);
  launch_gemm(F, 0, 256, WCAT, BCAT, UV, 0, 1024, 2048, 1024, 256, 1, stream);
  edge_agg<<<dim3(2*1024), 256, 0, stream>>>(UV, knn, 1024, 32, 512, F);
  launch_gemm(F, 0, 512, e2_Wo, e2_bo, G, 0, 512, 2048, 512, 512, 1, stream);
  upsample_kernel<1024,512><<<2048, 256, 0, stream>>>(x, xsp, G, FUSED, 256);

  // ---- encoder 3: S=2048, k=64, 6->128->256->512, proj 512 ----
  knn_kernel<2048,64><<<1024, 256, 0, stream>>>(xsp, knn);
  wcat_prep<<<256, 256, 0, stream>>>(e3_W0, e3_b0, 6, 128, WCAT, BCAT);
  launch_gemm(xs6, (long)2048*6, 6, WCAT, BCAT, UV, (long)2048*256, 256, 2048, 256, 6, 2, stream);
  edge_agg<<<dim3(2*2048), 128, 0, stream>>>(UV, knn, 2048, 64, 128, F);
  wcat_prep<<<256, 256, 0, stream>>>(e3_W1, e3_b1, 128, 256, WCAT, BCAT);
  launch_gemm(F, 0, 128, WCAT, BCAT, UV, 0, 512, 4096, 512, 128, 1, stream);
  edge_agg<<<dim3(2*2048), 256, 0, stream>>>(UV, knn, 2048, 64, 256, F);
  wcat_prep<<<256, 256, 0, stream>>>(e3_W2, e3_b2, 256, 512, WCAT, BCAT);
  launch_gemm(F, 0, 256, WCAT, BCAT, UV, 0, 1024, 4096, 1024, 256, 1, stream);
  edge_agg<<<dim3(2*2048), 256, 0, stream>>>(UV, knn, 2048, 64, 512, F);
  launch_gemm(F, 0, 512, e3_Wo, e3_bo, G, 0, 512, 4096, 512, 512, 1, stream);
  upsample_kernel<2048,512><<<2048, 256, 0, stream>>>(x, xsp, G, FUSED, 768);

  // ---- fusion MLP + GroupNorm + pos-enc ----
  launch_gemm(FUSED, 0, 1280, f_W1, f_b1, T, 0, 512, 8192, 512, 1280, 1, stream);
  gn_kernel<<<1024, 256, 0, stream>>>(T, g1_w, g1_b, H1, 0);
  launch_gemm(H1, 0, 512, f_W2, f_b2, T2, 0, 512, 8192, 512, 512, 1, stream);
  gn_kernel<<<1024, 256, 0, stream>>>(T2, g2_w, g2_b, (float*)d_out, 1);
}

// Round 3
// 2659.974 us; speedup vs baseline: 1.0207x; 1.0207x over previous
//
#include <hip/hip_runtime.h>
#include <math.h>

// ---------------- workspace offsets (bytes) ----------------
#define OFF_CENT   0x0        // int [2][2048]                     16 KB
#define OFF_XSP    0x20000    // float4 [2][2048] coords            64 KB
#define OFF_XS6    0x40000    // float [2][2048][6]                 96 KB
#define OFF_KNN    0x60000    // int [2][2048][64] max               1 MB
#define OFF_F      0x180000   // float [2*2048][512] max             8 MB
#define OFF_UV     0xA00000   // float [2*2048][1024] max           16 MB
#define OFF_G      0x1A00000  // float [2*2048][512] max             8 MB
#define OFF_WCAT   0x2200000  // float [256][1024] max               1 MB (+slack)
#define OFF_BCAT   0x2400000  // float [1024]
#define OFF_FUSED  0x2500000  // float [2][4096][1280]              42 MB  -> ws end 77 MB
#define OFF_T      0x180000   // reuse (post-encoder)  float [8192][512]
#define OFF_H1     0x1200000  // reuse                 float [8192][512]
#define OFF_T2     0x2200000  // reuse                 float [8192][512]

// ---------------- helpers ----------------
__device__ __forceinline__ unsigned fkey_flip(float f) {
  unsigned u = __float_as_uint(f);
  return u ^ ((u >> 31) ? 0xFFFFFFFFu : 0x80000000u);
}
__device__ __forceinline__ float fkey_unflip(unsigned k) {
  unsigned u = k ^ ((k >> 31) ? 0x80000000u : 0xFFFFFFFFu);
  return __uint_as_float(u);
}

// DPP-based wave64 max: v_max_f32 with row_shr / row_bcast operands.
// ctrl must be a compile-time constant -> template parameter.
template<int CTRL>
__device__ __forceinline__ float dpp_max_step(float v) {
  int t = __builtin_amdgcn_update_dpp(__float_as_int(v), __float_as_int(v),
                                      CTRL, 0xf, 0xf, false);
  return fmaxf(v, __int_as_float(t));
}
__device__ __forceinline__ float wave64_max(float v) {
  v = dpp_max_step<0x111>(v);  // row_shr:1
  v = dpp_max_step<0x112>(v);  // row_shr:2
  v = dpp_max_step<0x114>(v);  // row_shr:4
  v = dpp_max_step<0x118>(v);  // row_shr:8
  v = dpp_max_step<0x142>(v);  // row_bcast:15
  v = dpp_max_step<0x143>(v);  // row_bcast:31
  // lane 63 now holds the wave max; broadcast it.
  return __int_as_float(__builtin_amdgcn_readlane(__float_as_int(v), 63));
}

// ---------------- FPS: one block per batch, sequential 2048 steps ----------------
// Value-only DPP max reduction + exact-equality atomicMin for the argmax index
// (ties -> lowest global index, matching jnp.argmax first-occurrence).
__global__ __launch_bounds__(512) void fps_kernel(const float* __restrict__ x,
                                                  int* __restrict__ cent)
{
  int b = blockIdx.x, tid = threadIdx.x;
  __shared__ float LX[4096], LY[4096], LZ[4096];
  __shared__ float slotf[8];
  __shared__ unsigned idxslot[2];
  float px[8], py[8], pz[8], dist[8];
#pragma unroll
  for (int i = 0; i < 8; ++i) {
    int p = tid + 512 * i;
    const float* r = x + ((long)b * 4096 + p) * 6;
    px[i] = r[0]; py[i] = r[1]; pz[i] = r[2];
    LX[p] = px[i]; LY[p] = py[i]; LZ[p] = pz[i];
    dist[i] = 1e10f;
  }
  if (tid == 0) {
    cent[b * 2048] = 0;
    idxslot[0] = 0xFFFFFFFFu; idxslot[1] = 0xFFFFFFFFu;
  }
  __syncthreads();
  float cx = LX[0], cy = LY[0], cz = LZ[0];
  int wid = tid >> 6, lane = tid & 63;
  for (int j = 1; j < 2048; ++j) {
    float m = -1.0f;
#pragma unroll
    for (int i = 0; i < 8; ++i) {
      // exact replica of sum((xyz-c)**2, -1): ((dx*dx+dy*dy)+dz*dz), no FMA
      float dx = __fsub_rn(px[i], cx);
      float dy = __fsub_rn(py[i], cy);
      float dz = __fsub_rn(pz[i], cz);
      float d  = __fadd_rn(__fadd_rn(__fmul_rn(dx,dx), __fmul_rn(dy,dy)), __fmul_rn(dz,dz));
      float nd = fminf(dist[i], d);
      dist[i] = nd;
      m = fmaxf(m, nd);
    }
    m = wave64_max(m);                 // ~6 DPP+max, VALU latency only
    if (lane == 0) slotf[wid] = m;
    __syncthreads();                   // barrier A: per-wave maxima visible
    float4 s0 = *(const float4*)&slotf[0];
    float4 s1 = *(const float4*)&slotf[4];
    float gmax = fmaxf(fmaxf(fmaxf(s0.x, s0.y), fmaxf(s0.z, s0.w)),
                       fmaxf(fmaxf(s1.x, s1.y), fmaxf(s1.z, s1.w)));
    unsigned il = 0xFFFFFFFFu;
#pragma unroll
    for (int i = 7; i >= 0; --i)       // descending: lowest i wins within thread
      if (dist[i] == gmax) il = (unsigned)(tid + 512 * i);
    if (il != 0xFFFFFFFFu) atomicMin(&idxslot[j & 1], il);
    if (tid == 0) idxslot[(j + 1) & 1] = 0xFFFFFFFFu;  // reset the other buffer
    __syncthreads();                   // barrier B: winner index visible
    unsigned idx = idxslot[j & 1];
    cx = LX[idx]; cy = LY[idx]; cz = LZ[idx];
    if (tid == 0) cent[b * 2048 + j] = idx;
  }
}

// ---------------- gather subsampled points ----------------
__global__ void gather_xs_kernel(const float* __restrict__ x, const int* __restrict__ cent,
                                 float* __restrict__ xs6, float4* __restrict__ xsp)
{
  int t = blockIdx.x * 256 + threadIdx.x;
  if (t >= 2 * 2048) return;
  int b = t >> 11;
  int p = cent[t];
  const float* src = x + ((long)b * 4096 + p) * 6;
  float* dst = xs6 + (long)t * 6;
#pragma unroll
  for (int c = 0; c < 6; ++c) dst[c] = src[c];
  xsp[t] = make_float4(src[0], src[1], src[2], 0.0f);
}

// ---------------- kNN: one wave per query ----------------
template<int S, int K>
__global__ __launch_bounds__(256) void knn_kernel(const float4* __restrict__ xsp,
                                                  int* __restrict__ out)
{
  constexpr int NI = S / 64;
  __shared__ float4 P[S];
  int b = (blockIdx.x * 4) / S;
  int wid = threadIdx.x >> 6, lane = threadIdx.x & 63;
  int s = (blockIdx.x * 4 + wid) & (S - 1);
  for (int i = threadIdx.x; i < S; i += 256) P[i] = xsp[b * 2048 + i];
  __syncthreads();
  float4 Q = P[s];
  float saq = __fadd_rn(__fadd_rn(__fmul_rn(Q.x,Q.x), __fmul_rn(Q.y,Q.y)), __fmul_rn(Q.z,Q.z));
  float dd[NI];
#pragma unroll
  for (int i = 0; i < NI; ++i) {
    float4 c = P[i * 64 + lane];
    float sac = __fadd_rn(__fadd_rn(__fmul_rn(c.x,c.x), __fmul_rn(c.y,c.y)), __fmul_rn(c.z,c.z));
    float dot = __fadd_rn(__fadd_rn(__fmul_rn(Q.x,c.x), __fmul_rn(Q.y,c.y)), __fmul_rn(Q.z,c.z));
    dd[i] = __fsub_rn(__fadd_rn(saq, sac), __fmul_rn(2.0f, dot));
  }
  long obase = ((long)b * S + s) * K;
  for (int t = 0; t < K; ++t) {
    float bv = INFINITY; int bi = 0;
#pragma unroll
    for (int i = 0; i < NI; ++i) if (dd[i] < bv) { bv = dd[i]; bi = i; }
    unsigned long long key = ((unsigned long long)fkey_flip(bv) << 32)
                           | (unsigned)(bi * 64 + lane);
#pragma unroll
    for (int m = 32; m; m >>= 1) {
      unsigned long long o = __shfl_xor(key, m, 64);
      if (o < key) key = o;
    }
    unsigned cand = (unsigned)key;
    if ((int)(cand & 63) == lane) {
      int slot = cand >> 6;
#pragma unroll
      for (int i = 0; i < NI; ++i) if (i == slot) dd[i] = INFINITY;
    }
    if (lane == 0) out[obase + t] = (int)cand;
  }
}

// ---------------- Wcat prep: [2C,C'] -> [C, 2C'] with (Wa-Wb | Wb), bias -> (b | 0) ----------------
__global__ void wcat_prep(const float* __restrict__ W, const float* __restrict__ bias,
                          int C, int Cp, float* __restrict__ Wcat, float* __restrict__ bcat)
{
  int n2 = 2 * Cp;
  int total = C * n2;
  for (int t = blockIdx.x * 256 + threadIdx.x; t < total + n2; t += gridDim.x * 256) {
    if (t < total) {
      int c = t / n2, n = t % n2;
      Wcat[t] = (n < Cp) ? (W[c * Cp + n] - W[(C + c) * Cp + n]) : W[(C + c) * Cp + (n - Cp)];
    } else {
      int n = t - total;
      bcat[n] = (n < Cp) ? bias[n] : 0.0f;
    }
  }
}

// ---------------- generic fp32 GEMM: C = A[M,K] * W[K,N] + bias ----------------
__global__ __launch_bounds__(256) void gemm_bias(
    const float* __restrict__ A, long strideA, int lda,
    const float* __restrict__ W, int N, int K,
    const float* __restrict__ bias,
    float* __restrict__ C, long strideC, int ldc)
{
  A += (long)blockIdx.z * strideA;
  C += (long)blockIdx.z * strideC;
  int rowBase = blockIdx.x * 64, colBase = blockIdx.y * 64;
  __shared__ float As[16][68];
  __shared__ float Ws[16][68];
  int tid = threadIdx.x;
  int tx = tid & 15, ty = tid >> 4;
  float acc[4][4] = {};
  for (int k0 = 0; k0 < K; k0 += 16) {
    {
      int r = tid >> 2, c0 = (tid & 3) * 4;
      const float* Ar = A + (long)(rowBase + r) * lda + k0 + c0;
#pragma unroll
      for (int u = 0; u < 4; ++u) {
        float val = 0.0f;
        if (k0 + c0 + u < K) val = Ar[u];
        As[c0 + u][r] = val;
      }
    }
    {
      int c = tid & 63, kr = tid >> 6;
#pragma unroll
      for (int u = 0; u < 4; ++u) {
        int kk = kr + u * 4;
        float val = 0.0f;
        if (k0 + kk < K) val = W[(long)(k0 + kk) * N + colBase + c];
        Ws[kk][c] = val;
      }
    }
    __syncthreads();
#pragma unroll
    for (int kk = 0; kk < 16; ++kk) {
      float4 av = *(const float4*)&As[kk][ty * 4];
      float4 wv = *(const float4*)&Ws[kk][tx * 4];
      float a_[4] = {av.x, av.y, av.z, av.w};
      float w_[4] = {wv.x, wv.y, wv.z, wv.w};
#pragma unroll
      for (int i = 0; i < 4; ++i)
#pragma unroll
        for (int j = 0; j < 4; ++j)
          acc[i][j] = fmaf(a_[i], w_[j], acc[i][j]);
    }
    __syncthreads();
  }
#pragma unroll
  for (int i = 0; i < 4; ++i) {
    int r = rowBase + ty * 4 + i;
    int c0 = colBase + tx * 4;
    float4 o;
    o.x = acc[i][0] + bias[c0 + 0];
    o.y = acc[i][1] + bias[c0 + 1];
    o.z = acc[i][2] + bias[c0 + 2];
    o.w = acc[i][3] + bias[c0 + 3];
    *(float4*)&C[(long)r * ldc + c0] = o;
  }
}

// ---------------- edge aggregation: F[s] = relu(u[s] + max_j v[nbr_j]) ----------------
__global__ void edge_agg(const float* __restrict__ UV, const int* __restrict__ idx,
                         int S, int k, int Cp, float* __restrict__ F)
{
  int bs = blockIdx.x;
  int b = bs / S;
  __shared__ int nb[64];
  if ((int)threadIdx.x < k) nb[threadIdx.x] = idx[(long)bs * k + threadIdx.x];
  __syncthreads();
  int ld = 2 * Cp;
  const float* Ub = UV + (long)bs * ld;
  for (int c = threadIdx.x; c < Cp; c += blockDim.x) {
    float m = -INFINITY;
    for (int j = 0; j < k; ++j) {
      float v = UV[(long)(b * S + nb[j]) * ld + Cp + c];
      m = fmaxf(m, v);
    }
    float r = Ub[c] + m;
    F[(long)bs * Cp + c] = r > 0.0f ? r : 0.0f;
  }
}

// ---------------- upsample: 3-NN inverse-distance interp, writes into fused concat ----------------
template<int S, int CP>
__global__ __launch_bounds__(256) void upsample_kernel(
    const float* __restrict__ x, const float4* __restrict__ xsp,
    const float* __restrict__ G, float* __restrict__ fused, int colOff)
{
  constexpr int NI = S / 64;
  __shared__ float4 P[S];
  int b = (blockIdx.x * 4) >> 12;
  int wid = threadIdx.x >> 6, lane = threadIdx.x & 63;
  int n = (blockIdx.x * 4 + wid) & 4095;
  for (int i = threadIdx.x; i < S; i += 256) P[i] = xsp[b * 2048 + i];
  __syncthreads();
  const float* q = x + ((long)b * 4096 + n) * 6;
  float qx = q[0], qy = q[1], qz = q[2];
  float saq = __fadd_rn(__fadd_rn(__fmul_rn(qx,qx), __fmul_rn(qy,qy)), __fmul_rn(qz,qz));
  float dd[NI];
#pragma unroll
  for (int i = 0; i < NI; ++i) {
    float4 c = P[i * 64 + lane];
    float sac = __fadd_rn(__fadd_rn(__fmul_rn(c.x,c.x), __fmul_rn(c.y,c.y)), __fmul_rn(c.z,c.z));
    float dot = __fadd_rn(__fadd_rn(__fmul_rn(qx,c.x), __fmul_rn(qy,c.y)), __fmul_rn(qz,c.z));
    dd[i] = __fsub_rn(__fadd_rn(saq, sac), __fmul_rn(2.0f, dot));
  }
  int id[3]; float w[3];
  for (int t = 0; t < 3; ++t) {
    float bv = INFINITY; int bi = 0;
#pragma unroll
    for (int i = 0; i < NI; ++i) if (dd[i] < bv) { bv = dd[i]; bi = i; }
    unsigned long long key = ((unsigned long long)fkey_flip(bv) << 32)
                           | (unsigned)(bi * 64 + lane);
#pragma unroll
    for (int m = 32; m; m >>= 1) {
      unsigned long long o = __shfl_xor(key, m, 64);
      if (o < key) key = o;
    }
    unsigned cand = (unsigned)key;
    float d2 = fkey_unflip((unsigned)(key >> 32));
    float d = __fsqrt_rn(fmaxf(d2, 0.0f));
    id[t] = (int)cand;
    w[t] = 1.0f / __fadd_rn(d, 1e-8f);
    if ((int)(cand & 63) == lane) {
      int slot = cand >> 6;
#pragma unroll
      for (int i = 0; i < NI; ++i) if (i == slot) dd[i] = INFINITY;
    }
  }
  float wsum = __fadd_rn(__fadd_rn(w[0], w[1]), w[2]);
  float w0 = w[0] / wsum, w1 = w[1] / wsum, w2 = w[2] / wsum;
  const float* g0 = G + (long)(b * S + id[0]) * CP;
  const float* g1 = G + (long)(b * S + id[1]) * CP;
  const float* g2 = G + (long)(b * S + id[2]) * CP;
  float* orow = fused + ((long)b * 4096 + n) * 1280 + colOff;
#pragma unroll
  for (int t = 0; t < CP / 64; ++t) {
    int c = lane + 64 * t;
    float v = __fadd_rn(__fadd_rn(__fmul_rn(w0, g0[c]), __fmul_rn(w1, g1[c])),
                        __fmul_rn(w2, g2[c]));
    orow[c] = v;
  }
}

// ---------------- GroupNorm(32,512) + relu (+ optional pos-enc), one group per thread ----------------
__global__ __launch_bounds__(256) void gn_kernel(const float* __restrict__ T,
    const float* __restrict__ gw, const float* __restrict__ gb,
    float* __restrict__ out, int addPos)
{
  int t = blockIdx.x * 256 + threadIdx.x;
  int row = t >> 5, g = t & 31;
  const float* p = T + (long)row * 512 + g * 16;
  float v[16];
#pragma unroll
  for (int i = 0; i < 4; ++i) {
    float4 f = *(const float4*)(p + i * 4);
    v[i*4+0] = f.x; v[i*4+1] = f.y; v[i*4+2] = f.z; v[i*4+3] = f.w;
  }
  float s = 0.0f;
#pragma unroll
  for (int i = 0; i < 16; ++i) s += v[i];
  float mu = s * 0.0625f;
  float var = 0.0f;
#pragma unroll
  for (int i = 0; i < 16; ++i) { float d = v[i] - mu; var += d * d; }
  var *= 0.0625f;
  float inv = 1.0f / sqrtf(var + 1e-5f);
  int cbase = g * 16;
  int n = row & 4095;
  float o[16];
#pragma unroll
  for (int i = 0; i < 16; ++i) {
    int c = cbase + i;
    float y = (v[i] - mu) * inv * gw[c] + gb[c];
    y = y > 0.0f ? y : 0.0f;
    if (addPos) {
      int half = c >> 1;
      float div = expf((float)(2 * half) * -0.017988946039016358f); // -ln(10000)/512
      float ang = (float)n * div;
      y += (c & 1) ? cosf(ang) : sinf(ang);
    }
    o[i] = y;
  }
  float* d = out + (long)row * 512 + cbase;
#pragma unroll
  for (int i = 0; i < 4; ++i) {
    float4 f; f.x = o[i*4+0]; f.y = o[i*4+1]; f.z = o[i*4+2]; f.w = o[i*4+3];
    *(float4*)(d + i * 4) = f;
  }
}

// ---------------- host-side launch helpers ----------------
static inline void launch_gemm(const float* A, long strideA, int lda,
                               const float* W, const float* bias,
                               float* C, long strideC, int ldc,
                               int Mb, int N, int K, int nb, hipStream_t s)
{
  dim3 grid(Mb / 64, N / 64, nb);
  gemm_bias<<<grid, 256, 0, s>>>(A, strideA, lda, W, N, K, bias, C, strideC, ldc);
}

extern "C" void kernel_launch(void* const* d_in, const int* in_sizes, int n_in,
                              void* d_out, int out_size, void* d_ws, size_t ws_size,
                              hipStream_t stream)
{
  const float* x     = (const float*)d_in[0];
  const float* e1_W0 = (const float*)d_in[1];  const float* e1_b0 = (const float*)d_in[2];
  const float* e1_W1 = (const float*)d_in[3];  const float* e1_b1 = (const float*)d_in[4];
  const float* e1_Wo = (const float*)d_in[5];  const float* e1_bo = (const float*)d_in[6];
  const float* e2_W0 = (const float*)d_in[7];  const float* e2_b0 = (const float*)d_in[8];
  const float* e2_W1 = (const float*)d_in[9];  const float* e2_b1 = (const float*)d_in[10];
  const float* e2_Wo = (const float*)d_in[11]; const float* e2_bo = (const float*)d_in[12];
  const float* e3_W0 = (const float*)d_in[13]; const float* e3_b0 = (const float*)d_in[14];
  const float* e3_W1 = (const float*)d_in[15]; const float* e3_b1 = (const float*)d_in[16];
  const float* e3_W2 = (const float*)d_in[17]; const float* e3_b2 = (const float*)d_in[18];
  const float* e3_Wo = (const float*)d_in[19]; const float* e3_bo = (const float*)d_in[20];
  const float* f_W1  = (const float*)d_in[21]; const float* f_b1  = (const float*)d_in[22];
  const float* g1_w  = (const float*)d_in[23]; const float* g1_b  = (const float*)d_in[24];
  const float* f_W2  = (const float*)d_in[25]; const float* f_b2  = (const float*)d_in[26];
  const float* g2_w  = (const float*)d_in[27]; const float* g2_b  = (const float*)d_in[28];

  char* ws = (char*)d_ws;
  int*    cent  = (int*)(ws + OFF_CENT);
  float4* xsp   = (float4*)(ws + OFF_XSP);
  float*  xs6   = (float*)(ws + OFF_XS6);
  int*    knn   = (int*)(ws + OFF_KNN);
  float*  F     = (float*)(ws + OFF_F);
  float*  UV    = (float*)(ws + OFF_UV);
  float*  G     = (float*)(ws + OFF_G);
  float*  WCAT  = (float*)(ws + OFF_WCAT);
  float*  BCAT  = (float*)(ws + OFF_BCAT);
  float*  FUSED = (float*)(ws + OFF_FUSED);
  float*  T     = (float*)(ws + OFF_T);
  float*  H1    = (float*)(ws + OFF_H1);
  float*  T2    = (float*)(ws + OFF_T2);

  fps_kernel<<<2, 512, 0, stream>>>(x, cent);
  gather_xs_kernel<<<16, 256, 0, stream>>>(x, cent, xs6, xsp);

  // ---- encoder 1: S=512, k=16, 6->128->256, proj 256 ----
  knn_kernel<512,16><<<256, 256, 0, stream>>>(xsp, knn);
  wcat_prep<<<256, 256, 0, stream>>>(e1_W0, e1_b0, 6, 128, WCAT, BCAT);
  launch_gemm(xs6, (long)2048*6, 6, WCAT, BCAT, UV, (long)512*256, 256, 512, 256, 6, 2, stream);
  edge_agg<<<dim3(2*512), 128, 0, stream>>>(UV, knn, 512, 16, 128, F);
  wcat_prep<<<256, 256, 0, stream>>>(e1_W1, e1_b1, 128, 256, WCAT, BCAT);
  launch_gemm(F, 0, 128, WCAT, BCAT, UV, 0, 512, 1024, 512, 128, 1, stream);
  edge_agg<<<dim3(2*512), 256, 0, stream>>>(UV, knn, 512, 16, 256, F);
  launch_gemm(F, 0, 256, e1_Wo, e1_bo, G, 0, 256, 1024, 256, 256, 1, stream);
  upsample_kernel<512,256><<<2048, 256, 0, stream>>>(x, xsp, G, FUSED, 0);

  // ---- encoder 2: S=1024, k=32, 6->256->512, proj 512 ----
  knn_kernel<1024,32><<<512, 256, 0, stream>>>(xsp, knn);
  wcat_prep<<<256, 256, 0, stream>>>(e2_W0, e2_b0, 6, 256, WCAT, BCAT);
  launch_gemm(xs6, (long)2048*6, 6, WCAT, BCAT, UV, (long)1024*512, 512, 1024, 512, 6, 2, stream);
  edge_agg<<<dim3(2*1024), 256, 0, stream>>>(UV, knn, 1024, 32, 256, F);
  wcat_prep<<<256, 256, 0, stream>>>(e2_W1, e2_b1, 256, 512, WCAT, BCAT);
  launch_gemm(F, 0, 256, WCAT, BCAT, UV, 0, 1024, 2048, 1024, 256, 1, stream);
  edge_agg<<<dim3(2*1024), 256, 0, stream>>>(UV, knn, 1024, 32, 512, F);
  launch_gemm(F, 0, 512, e2_Wo, e2_bo, G, 0, 512, 2048, 512, 512, 1, stream);
  upsample_kernel<1024,512><<<2048, 256, 0, stream>>>(x, xsp, G, FUSED, 256);

  // ---- encoder 3: S=2048, k=64, 6->128->256->512, proj 512 ----
  knn_kernel<2048,64><<<1024, 256, 0, stream>>>(xsp, knn);
  wcat_prep<<<256, 256, 0, stream>>>(e3_W0, e3_b0, 6, 128, WCAT, BCAT);
  launch_gemm(xs6, (long)2048*6, 6, WCAT, BCAT, UV, (long)2048*256, 256, 2048, 256, 6, 2, stream);
  edge_agg<<<dim3(2*2048), 128, 0, stream>>>(UV, knn, 2048, 64, 128, F);
  wcat_prep<<<256, 256, 0, stream>>>(e3_W1, e3_b1, 128, 256, WCAT, BCAT);
  launch_gemm(F, 0, 128, WCAT, BCAT, UV, 0, 512, 4096, 512, 128, 1, stream);
  edge_agg<<<dim3(2*2048), 256, 0, stream>>>(UV, knn, 2048, 64, 256, F);
  wcat_prep<<<256, 256, 0, stream>>>(e3_W2, e3_b2, 256, 512, WCAT, BCAT);
  launch_gemm(F, 0, 256, WCAT, BCAT, UV, 0, 1024, 4096, 1024, 256, 1, stream);
  edge_agg<<<dim3(2*2048), 256, 0, stream>>>(UV, knn, 2048, 64, 512, F);
  launch_gemm(F, 0, 512, e3_Wo, e3_bo, G, 0, 512, 4096, 512, 512, 1, stream);
  upsample_kernel<2048,512><<<2048, 256, 0, stream>>>(x, xsp, G, FUSED, 768);

  // ---- fusion MLP + GroupNorm + pos-enc ----
  launch_gemm(FUSED, 0, 1280, f_W1, f_b1, T, 0, 512, 8192, 512, 1280, 1, stream);
  gn_kernel<<<1024, 256, 0, stream>>>(T, g1_w, g1_b, H1, 0);
  launch_gemm(H1, 0, 512, f_W2, f_b2, T2, 0, 512, 8192, 512, 512, 1, stream);
  gn_kernel<<<1024, 256, 0, stream>>>(T2, g2_w, g2_b, (float*)d_out, 1);
}

// Round 4
// 2439.107 us; speedup vs baseline: 1.1132x; 1.0906x over previous
//
#include <hip/hip_runtime.h>
#include <math.h>

// ---------------- workspace offsets (bytes) ----------------
#define OFF_CENT   0x0        // int [2][2048]                     16 KB
#define OFF_XSP    0x20000    // float4 [2][2048] coords            64 KB
#define OFF_XS6    0x40000    // float [2][2048][6]                 96 KB
#define OFF_KNN    0x60000    // int [2][2048][64] max               1 MB
#define OFF_F      0x180000   // float [2*2048][512] max             8 MB
#define OFF_UV     0xA00000   // float [2*2048][1024] max           16 MB
#define OFF_G      0x1A00000  // float [2*2048][512] max             8 MB
#define OFF_WCAT   0x2200000  // float [256][1024] max               1 MB (+slack)
#define OFF_BCAT   0x2400000  // float [1024]
#define OFF_FUSED  0x2500000  // float [2][4096][1280]              42 MB  -> ws end 77 MB
#define OFF_T      0x180000   // reuse (post-encoder)  float [8192][512]
#define OFF_H1     0x1200000  // reuse                 float [8192][512]
#define OFF_T2     0x2200000  // reuse                 float [8192][512]

// ---------------- helpers ----------------
__device__ __forceinline__ unsigned fkey_flip(float f) {
  unsigned u = __float_as_uint(f);
  return u ^ ((u >> 31) ? 0xFFFFFFFFu : 0x80000000u);
}
__device__ __forceinline__ float fkey_unflip(unsigned k) {
  unsigned u = k ^ ((k >> 31) ? 0x80000000u : 0xFFFFFFFFu);
  return __uint_as_float(u);
}

// DPP-based wave64 reductions (row_shr then row_bcast; lane 63 ends with result).
template<int CTRL>
__device__ __forceinline__ float dpp_max_stepf(float v) {
  int t = __builtin_amdgcn_update_dpp(__float_as_int(v), __float_as_int(v),
                                      CTRL, 0xf, 0xf, false);
  return fmaxf(v, __int_as_float(t));
}
__device__ __forceinline__ float wave64_max(float v) {
  v = dpp_max_stepf<0x111>(v);  // row_shr:1
  v = dpp_max_stepf<0x112>(v);  // row_shr:2
  v = dpp_max_stepf<0x114>(v);  // row_shr:4
  v = dpp_max_stepf<0x118>(v);  // row_shr:8
  v = dpp_max_stepf<0x142>(v);  // row_bcast:15
  v = dpp_max_stepf<0x143>(v);  // row_bcast:31
  return __int_as_float(__builtin_amdgcn_readlane(__float_as_int(v), 63));
}
template<int CTRL>
__device__ __forceinline__ unsigned dpp_min_stepu(unsigned v) {
  unsigned t = (unsigned)__builtin_amdgcn_update_dpp((int)v, (int)v,
                                                     CTRL, 0xf, 0xf, false);
  return v < t ? v : t;
}
__device__ __forceinline__ unsigned wave64_min_u32(unsigned v) {
  v = dpp_min_stepu<0x111>(v);
  v = dpp_min_stepu<0x112>(v);
  v = dpp_min_stepu<0x114>(v);
  v = dpp_min_stepu<0x118>(v);
  v = dpp_min_stepu<0x142>(v);
  v = dpp_min_stepu<0x143>(v);
  return (unsigned)__builtin_amdgcn_readlane((int)v, 63);
}

// ---------------- FPS: one block per batch, sequential 2048 steps ----------------
// One barrier per iteration, no atomics. Per-wave in-register (value,idx) reduce;
// 4 packed u64 slots (double-buffered); every thread self-selects the winner.
// Distances are >= 0 so raw fp32 bits compare like values; ~idx gives ties->lowest.
__global__ __launch_bounds__(256) void fps_kernel(const float* __restrict__ x,
                                                  int* __restrict__ cent)
{
  int b = blockIdx.x, tid = threadIdx.x;
  __shared__ float4 C4[4096];
  __shared__ __align__(16) unsigned long long slots[2][4];
  float px[16], py[16], pz[16], dist[16];
#pragma unroll
  for (int i = 0; i < 16; ++i) {
    int p = tid + 256 * i;
    const float* r = x + ((long)b * 4096 + p) * 6;
    px[i] = r[0]; py[i] = r[1]; pz[i] = r[2];
    C4[p] = make_float4(px[i], py[i], pz[i], 0.0f);
    dist[i] = 1e10f;
  }
  if (tid == 0) cent[b * 2048] = 0;
  __syncthreads();
  float4 c0 = C4[0];
  float cx = c0.x, cy = c0.y, cz = c0.z;
  int wid = tid >> 6, lane = tid & 63;
  for (int j = 1; j < 2048; ++j) {
    float m = -1.0f;
#pragma unroll
    for (int i = 0; i < 16; ++i) {
      // exact replica of sum((xyz-c)**2, -1): ((dx*dx+dy*dy)+dz*dz), no FMA
      float dx = __fsub_rn(px[i], cx);
      float dy = __fsub_rn(py[i], cy);
      float dz = __fsub_rn(pz[i], cz);
      float d  = __fadd_rn(__fadd_rn(__fmul_rn(dx,dx), __fmul_rn(dy,dy)), __fmul_rn(dz,dz));
      float nd = fminf(dist[i], d);
      dist[i] = nd;
      m = fmaxf(m, nd);
    }
    float wm = wave64_max(m);
    unsigned il = 0xFFFFFFFFu;
#pragma unroll
    for (int i = 15; i >= 0; --i)      // descending: lowest i (lowest global p) wins
      if (dist[i] == wm) il = (unsigned)(tid + 256 * i);
    unsigned wi = wave64_min_u32(il);  // at least one lane matches within the wave
    if (lane == 0)
      slots[j & 1][wid] = ((unsigned long long)__float_as_uint(wm) << 32)
                        | (unsigned)(0xFFFFFFFFu - wi);
    __syncthreads();                   // the only barrier per iteration
    ulonglong2 s01 = *(const ulonglong2*)&slots[j & 1][0];
    ulonglong2 s23 = *(const ulonglong2*)&slots[j & 1][2];
    unsigned long long k0 = s01.x > s01.y ? s01.x : s01.y;
    unsigned long long k1 = s23.x > s23.y ? s23.x : s23.y;
    unsigned long long kk = k0 > k1 ? k0 : k1;
    unsigned idx = 0xFFFFFFFFu - (unsigned)kk;
    float4 c = C4[idx];
    cx = c.x; cy = c.y; cz = c.z;
    if (tid == 0) cent[b * 2048 + j] = idx;
  }
}

// ---------------- gather subsampled points ----------------
__global__ void gather_xs_kernel(const float* __restrict__ x, const int* __restrict__ cent,
                                 float* __restrict__ xs6, float4* __restrict__ xsp)
{
  int t = blockIdx.x * 256 + threadIdx.x;
  if (t >= 2 * 2048) return;
  int b = t >> 11;
  int p = cent[t];
  const float* src = x + ((long)b * 4096 + p) * 6;
  float* dst = xs6 + (long)t * 6;
#pragma unroll
  for (int c = 0; c < 6; ++c) dst[c] = src[c];
  xsp[t] = make_float4(src[0], src[1], src[2], 0.0f);
}

// ---------------- kNN: one wave per query ----------------
template<int S, int K>
__global__ __launch_bounds__(256) void knn_kernel(const float4* __restrict__ xsp,
                                                  int* __restrict__ out)
{
  constexpr int NI = S / 64;
  __shared__ float4 P[S];
  int b = (blockIdx.x * 4) / S;
  int wid = threadIdx.x >> 6, lane = threadIdx.x & 63;
  int s = (blockIdx.x * 4 + wid) & (S - 1);
  for (int i = threadIdx.x; i < S; i += 256) P[i] = xsp[b * 2048 + i];
  __syncthreads();
  float4 Q = P[s];
  float saq = __fadd_rn(__fadd_rn(__fmul_rn(Q.x,Q.x), __fmul_rn(Q.y,Q.y)), __fmul_rn(Q.z,Q.z));
  float dd[NI];
#pragma unroll
  for (int i = 0; i < NI; ++i) {
    float4 c = P[i * 64 + lane];
    float sac = __fadd_rn(__fadd_rn(__fmul_rn(c.x,c.x), __fmul_rn(c.y,c.y)), __fmul_rn(c.z,c.z));
    float dot = __fadd_rn(__fadd_rn(__fmul_rn(Q.x,c.x), __fmul_rn(Q.y,c.y)), __fmul_rn(Q.z,c.z));
    dd[i] = __fsub_rn(__fadd_rn(saq, sac), __fmul_rn(2.0f, dot));
  }
  long obase = ((long)b * S + s) * K;
  for (int t = 0; t < K; ++t) {
    float bv = INFINITY; int bi = 0;
#pragma unroll
    for (int i = 0; i < NI; ++i) if (dd[i] < bv) { bv = dd[i]; bi = i; }
    unsigned long long key = ((unsigned long long)fkey_flip(bv) << 32)
                           | (unsigned)(bi * 64 + lane);
#pragma unroll
    for (int m = 32; m; m >>= 1) {
      unsigned long long o = __shfl_xor(key, m, 64);
      if (o < key) key = o;
    }
    unsigned cand = (unsigned)key;
    if ((int)(cand & 63) == lane) {
      int slot = cand >> 6;
#pragma unroll
      for (int i = 0; i < NI; ++i) if (i == slot) dd[i] = INFINITY;
    }
    if (lane == 0) out[obase + t] = (int)cand;
  }
}

// ---------------- Wcat prep: [2C,C'] -> [C, 2C'] with (Wa-Wb | Wb), bias -> (b | 0) ----------------
__global__ void wcat_prep(const float* __restrict__ W, const float* __restrict__ bias,
                          int C, int Cp, float* __restrict__ Wcat, float* __restrict__ bcat)
{
  int n2 = 2 * Cp;
  int total = C * n2;
  for (int t = blockIdx.x * 256 + threadIdx.x; t < total + n2; t += gridDim.x * 256) {
    if (t < total) {
      int c = t / n2, n = t % n2;
      Wcat[t] = (n < Cp) ? (W[c * Cp + n] - W[(C + c) * Cp + n]) : W[(C + c) * Cp + (n - Cp)];
    } else {
      int n = t - total;
      bcat[n] = (n < Cp) ? bias[n] : 0.0f;
    }
  }
}

// ---------------- generic fp32 GEMM: C = A[M,K] * W[K,N] + bias ----------------
__global__ __launch_bounds__(256) void gemm_bias(
    const float* __restrict__ A, long strideA, int lda,
    const float* __restrict__ W, int N, int K,
    const float* __restrict__ bias,
    float* __restrict__ C, long strideC, int ldc)
{
  A += (long)blockIdx.z * strideA;
  C += (long)blockIdx.z * strideC;
  int rowBase = blockIdx.x * 64, colBase = blockIdx.y * 64;
  __shared__ float As[16][68];
  __shared__ float Ws[16][68];
  int tid = threadIdx.x;
  int tx = tid & 15, ty = tid >> 4;
  float acc[4][4] = {};
  for (int k0 = 0; k0 < K; k0 += 16) {
    {
      int r = tid >> 2, c0 = (tid & 3) * 4;
      const float* Ar = A + (long)(rowBase + r) * lda + k0 + c0;
#pragma unroll
      for (int u = 0; u < 4; ++u) {
        float val = 0.0f;
        if (k0 + c0 + u < K) val = Ar[u];
        As[c0 + u][r] = val;
      }
    }
    {
      int c = tid & 63, kr = tid >> 6;
#pragma unroll
      for (int u = 0; u < 4; ++u) {
        int kk = kr + u * 4;
        float val = 0.0f;
        if (k0 + kk < K) val = W[(long)(k0 + kk) * N + colBase + c];
        Ws[kk][c] = val;
      }
    }
    __syncthreads();
#pragma unroll
    for (int kk = 0; kk < 16; ++kk) {
      float4 av = *(const float4*)&As[kk][ty * 4];
      float4 wv = *(const float4*)&Ws[kk][tx * 4];
      float a_[4] = {av.x, av.y, av.z, av.w};
      float w_[4] = {wv.x, wv.y, wv.z, wv.w};
#pragma unroll
      for (int i = 0; i < 4; ++i)
#pragma unroll
        for (int j = 0; j < 4; ++j)
          acc[i][j] = fmaf(a_[i], w_[j], acc[i][j]);
    }
    __syncthreads();
  }
#pragma unroll
  for (int i = 0; i < 4; ++i) {
    int r = rowBase + ty * 4 + i;
    int c0 = colBase + tx * 4;
    float4 o;
    o.x = acc[i][0] + bias[c0 + 0];
    o.y = acc[i][1] + bias[c0 + 1];
    o.z = acc[i][2] + bias[c0 + 2];
    o.w = acc[i][3] + bias[c0 + 3];
    *(float4*)&C[(long)r * ldc + c0] = o;
  }
}

// ---------------- edge aggregation: F[s] = relu(u[s] + max_j v[nbr_j]) ----------------
__global__ void edge_agg(const float* __restrict__ UV, const int* __restrict__ idx,
                         int S, int k, int Cp, float* __restrict__ F)
{
  int bs = blockIdx.x;
  int b = bs / S;
  __shared__ int nb[64];
  if ((int)threadIdx.x < k) nb[threadIdx.x] = idx[(long)bs * k + threadIdx.x];
  __syncthreads();
  int ld = 2 * Cp;
  const float* Ub = UV + (long)bs * ld;
  for (int c = threadIdx.x; c < Cp; c += blockDim.x) {
    float m = -INFINITY;
    for (int j = 0; j < k; ++j) {
      float v = UV[(long)(b * S + nb[j]) * ld + Cp + c];
      m = fmaxf(m, v);
    }
    float r = Ub[c] + m;
    F[(long)bs * Cp + c] = r > 0.0f ? r : 0.0f;
  }
}

// ---------------- upsample: 3-NN inverse-distance interp, writes into fused concat ----------------
template<int S, int CP>
__global__ __launch_bounds__(256) void upsample_kernel(
    const float* __restrict__ x, const float4* __restrict__ xsp,
    const float* __restrict__ G, float* __restrict__ fused, int colOff)
{
  constexpr int NI = S / 64;
  __shared__ float4 P[S];
  int b = (blockIdx.x * 4) >> 12;
  int wid = threadIdx.x >> 6, lane = threadIdx.x & 63;
  int n = (blockIdx.x * 4 + wid) & 4095;
  for (int i = threadIdx.x; i < S; i += 256) P[i] = xsp[b * 2048 + i];
  __syncthreads();
  const float* q = x + ((long)b * 4096 + n) * 6;
  float qx = q[0], qy = q[1], qz = q[2];
  float saq = __fadd_rn(__fadd_rn(__fmul_rn(qx,qx), __fmul_rn(qy,qy)), __fmul_rn(qz,qz));
  float dd[NI];
#pragma unroll
  for (int i = 0; i < NI; ++i) {
    float4 c = P[i * 64 + lane];
    float sac = __fadd_rn(__fadd_rn(__fmul_rn(c.x,c.x), __fmul_rn(c.y,c.y)), __fmul_rn(c.z,c.z));
    float dot = __fadd_rn(__fadd_rn(__fmul_rn(qx,c.x), __fmul_rn(qy,c.y)), __fmul_rn(qz,c.z));
    dd[i] = __fsub_rn(__fadd_rn(saq, sac), __fmul_rn(2.0f, dot));
  }
  int id[3]; float w[3];
  for (int t = 0; t < 3; ++t) {
    float bv = INFINITY; int bi = 0;
#pragma unroll
    for (int i = 0; i < NI; ++i) if (dd[i] < bv) { bv = dd[i]; bi = i; }
    unsigned long long key = ((unsigned long long)fkey_flip(bv) << 32)
                           | (unsigned)(bi * 64 + lane);
#pragma unroll
    for (int m = 32; m; m >>= 1) {
      unsigned long long o = __shfl_xor(key, m, 64);
      if (o < key) key = o;
    }
    unsigned cand = (unsigned)key;
    float d2 = fkey_unflip((unsigned)(key >> 32));
    float d = __fsqrt_rn(fmaxf(d2, 0.0f));
    id[t] = (int)cand;
    w[t] = 1.0f / __fadd_rn(d, 1e-8f);
    if ((int)(cand & 63) == lane) {
      int slot = cand >> 6;
#pragma unroll
      for (int i = 0; i < NI; ++i) if (i == slot) dd[i] = INFINITY;
    }
  }
  float wsum = __fadd_rn(__fadd_rn(w[0], w[1]), w[2]);
  float w0 = w[0] / wsum, w1 = w[1] / wsum, w2 = w[2] / wsum;
  const float* g0 = G + (long)(b * S + id[0]) * CP;
  const float* g1 = G + (long)(b * S + id[1]) * CP;
  const float* g2 = G + (long)(b * S + id[2]) * CP;
  float* orow = fused + ((long)b * 4096 + n) * 1280 + colOff;
#pragma unroll
  for (int t = 0; t < CP / 64; ++t) {
    int c = lane + 64 * t;
    float v = __fadd_rn(__fadd_rn(__fmul_rn(w0, g0[c]), __fmul_rn(w1, g1[c])),
                        __fmul_rn(w2, g2[c]));
    orow[c] = v;
  }
}

// ---------------- GroupNorm(32,512) + relu (+ optional pos-enc), one group per thread ----------------
__global__ __launch_bounds__(256) void gn_kernel(const float* __restrict__ T,
    const float* __restrict__ gw, const float* __restrict__ gb,
    float* __restrict__ out, int addPos)
{
  int t = blockIdx.x * 256 + threadIdx.x;
  int row = t >> 5, g = t & 31;
  const float* p = T + (long)row * 512 + g * 16;
  float v[16];
#pragma unroll
  for (int i = 0; i < 4; ++i) {
    float4 f = *(const float4*)(p + i * 4);
    v[i*4+0] = f.x; v[i*4+1] = f.y; v[i*4+2] = f.z; v[i*4+3] = f.w;
  }
  float s = 0.0f;
#pragma unroll
  for (int i = 0; i < 16; ++i) s += v[i];
  float mu = s * 0.0625f;
  float var = 0.0f;
#pragma unroll
  for (int i = 0; i < 16; ++i) { float d = v[i] - mu; var += d * d; }
  var *= 0.0625f;
  float inv = 1.0f / sqrtf(var + 1e-5f);
  int cbase = g * 16;
  int n = row & 4095;
  float o[16];
#pragma unroll
  for (int i = 0; i < 16; ++i) {
    int c = cbase + i;
    float y = (v[i] - mu) * inv * gw[c] + gb[c];
    y = y > 0.0f ? y : 0.0f;
    if (addPos) {
      int half = c >> 1;
      float div = expf((float)(2 * half) * -0.017988946039016358f); // -ln(10000)/512
      float ang = (float)n * div;
      y += (c & 1) ? cosf(ang) : sinf(ang);
    }
    o[i] = y;
  }
  float* d = out + (long)row * 512 + cbase;
#pragma unroll
  for (int i = 0; i < 4; ++i) {
    float4 f; f.x = o[i*4+0]; f.y = o[i*4+1]; f.z = o[i*4+2]; f.w = o[i*4+3];
    *(float4*)(d + i * 4) = f;
  }
}

// ---------------- host-side launch helpers ----------------
static inline void launch_gemm(const float* A, long strideA, int lda,
                               const float* W, const float* bias,
                               float* C, long strideC, int ldc,
                               int Mb, int N, int K, int nb, hipStream_t s)
{
  dim3 grid(Mb / 64, N / 64, nb);
  gemm_bias<<<grid, 256, 0, s>>>(A, strideA, lda, W, N, K, bias, C, strideC, ldc);
}

extern "C" void kernel_launch(void* const* d_in, const int* in_sizes, int n_in,
                              void* d_out, int out_size, void* d_ws, size_t ws_size,
                              hipStream_t stream)
{
  const float* x     = (const float*)d_in[0];
  const float* e1_W0 = (const float*)d_in[1];  const float* e1_b0 = (const float*)d_in[2];
  const float* e1_W1 = (const float*)d_in[3];  const float* e1_b1 = (const float*)d_in[4];
  const float* e1_Wo = (const float*)d_in[5];  const float* e1_bo = (const float*)d_in[6];
  const float* e2_W0 = (const float*)d_in[7];  const float* e2_b0 = (const float*)d_in[8];
  const float* e2_W1 = (const float*)d_in[9];  const float* e2_b1 = (const float*)d_in[10];
  const float* e2_Wo = (const float*)d_in[11]; const float* e2_bo = (const float*)d_in[12];
  const float* e3_W0 = (const float*)d_in[13]; const float* e3_b0 = (const float*)d_in[14];
  const float* e3_W1 = (const float*)d_in[15]; const float* e3_b1 = (const float*)d_in[16];
  const float* e3_W2 = (const float*)d_in[17]; const float* e3_b2 = (const float*)d_in[18];
  const float* e3_Wo = (const float*)d_in[19]; const float* e3_bo = (const float*)d_in[20];
  const float* f_W1  = (const float*)d_in[21]; const float* f_b1  = (const float*)d_in[22];
  const float* g1_w  = (const float*)d_in[23]; const float* g1_b  = (const float*)d_in[24];
  const float* f_W2  = (const float*)d_in[25]; const float* f_b2  = (const float*)d_in[26];
  const float* g2_w  = (const float*)d_in[27]; const float* g2_b  = (const float*)d_in[28];

  char* ws = (char*)d_ws;
  int*    cent  = (int*)(ws + OFF_CENT);
  float4* xsp   = (float4*)(ws + OFF_XSP);
  float*  xs6   = (float*)(ws + OFF_XS6);
  int*    knn   = (int*)(ws + OFF_KNN);
  float*  F     = (float*)(ws + OFF_F);
  float*  UV    = (float*)(ws + OFF_UV);
  float*  G     = (float*)(ws + OFF_G);
  float*  WCAT  = (float*)(ws + OFF_WCAT);
  float*  BCAT  = (float*)(ws + OFF_BCAT);
  float*  FUSED = (float*)(ws + OFF_FUSED);
  float*  T     = (float*)(ws + OFF_T);
  float*  H1    = (float*)(ws + OFF_H1);
  float*  T2    = (float*)(ws + OFF_T2);

  fps_kernel<<<2, 256, 0, stream>>>(x, cent);
  gather_xs_kernel<<<16, 256, 0, stream>>>(x, cent, xs6, xsp);

  // ---- encoder 1: S=512, k=16, 6->128->256, proj 256 ----
  knn_kernel<512,16><<<256, 256, 0, stream>>>(xsp, knn);
  wcat_prep<<<256, 256, 0, stream>>>(e1_W0, e1_b0, 6, 128, WCAT, BCAT);
  launch_gemm(xs6, (long)2048*6, 6, WCAT, BCAT, UV, (long)512*256, 256, 512, 256, 6, 2, stream);
  edge_agg<<<dim3(2*512), 128, 0, stream>>>(UV, knn, 512, 16, 128, F);
  wcat_prep<<<256, 256, 0, stream>>>(e1_W1, e1_b1, 128, 256, WCAT, BCAT);
  launch_gemm(F, 0, 128, WCAT, BCAT, UV, 0, 512, 1024, 512, 128, 1, stream);
  edge_agg<<<dim3(2*512), 256, 0, stream>>>(UV, knn, 512, 16, 256, F);
  launch_gemm(F, 0, 256, e1_Wo, e1_bo, G, 0, 256, 1024, 256, 256, 1, stream);
  upsample_kernel<512,256><<<2048, 256, 0, stream>>>(x, xsp, G, FUSED, 0);

  // ---- encoder 2: S=1024, k=32, 6->256->512, proj 512 ----
  knn_kernel<1024,32><<<512, 256, 0, stream>>>(xsp, knn);
  wcat_prep<<<256, 256, 0, stream>>>(e2_W0, e2_b0, 6, 256, WCAT, BCAT);
  launch_gemm(xs6, (long)2048*6, 6, WCAT, BCAT, UV, (long)1024*512, 512, 1024, 512, 6, 2, stream);
  edge_agg<<<dim3(2*1024), 256, 0, stream>>>(UV, knn, 1024, 32, 256, F);
  wcat_prep<<<256, 256, 0, stream>>>(e2_W1, e2_b1, 256, 512, WCAT, BCAT);
  launch_gemm(F, 0, 256, WCAT, BCAT, UV, 0, 1024, 2048, 1024, 256, 1, stream);
  edge_agg<<<dim3(2*1024), 256, 0, stream>>>(UV, knn, 1024, 32, 512, F);
  launch_gemm(F, 0, 512, e2_Wo, e2_bo, G, 0, 512, 2048, 512, 512, 1, stream);
  upsample_kernel<1024,512><<<2048, 256, 0, stream>>>(x, xsp, G, FUSED, 256);

  // ---- encoder 3: S=2048, k=64, 6->128->256->512, proj 512 ----
  knn_kernel<2048,64><<<1024, 256, 0, stream>>>(xsp, knn);
  wcat_prep<<<256, 256, 0, stream>>>(e3_W0, e3_b0, 6, 128, WCAT, BCAT);
  launch_gemm(xs6, (long)2048*6, 6, WCAT, BCAT, UV, (long)2048*256, 256, 2048, 256, 6, 2, stream);
  edge_agg<<<dim3(2*2048), 128, 0, stream>>>(UV, knn, 2048, 64, 128, F);
  wcat_prep<<<256, 256, 0, stream>>>(e3_W1, e3_b1, 128, 256, WCAT, BCAT);
  launch_gemm(F, 0, 128, WCAT, BCAT, UV, 0, 512, 4096, 512, 128, 1, stream);
  edge_agg<<<dim3(2*2048), 256, 0, stream>>>(UV, knn, 2048, 64, 256, F);
  wcat_prep<<<256, 256, 0, stream>>>(e3_W2, e3_b2, 256, 512, WCAT, BCAT);
  launch_gemm(F, 0, 256, WCAT, BCAT, UV, 0, 1024, 4096, 1024, 256, 1, stream);
  edge_agg<<<dim3(2*2048), 256, 0, stream>>>(UV, knn, 2048, 64, 512, F);
  launch_gemm(F, 0, 512, e3_Wo, e3_bo, G, 0, 512, 4096, 512, 512, 1, stream);
  upsample_kernel<2048,512><<<2048, 256, 0, stream>>>(x, xsp, G, FUSED, 768);

  // ---- fusion MLP + GroupNorm + pos-enc ----
  launch_gemm(FUSED, 0, 1280, f_W1, f_b1, T, 0, 512, 8192, 512, 1280, 1, stream);
  gn_kernel<<<1024, 256, 0, stream>>>(T, g1_w, g1_b, H1, 0);
  launch_gemm(H1, 0, 512, f_W2, f_b2, T2, 0, 512, 8192, 512, 512, 1, stream);
  gn_kernel<<<1024, 256, 0, stream>>>(T2, g2_w, g2_b, (float*)d_out, 1);
}

// Round 5
// 2309.018 us; speedup vs baseline: 1.1759x; 1.0563x over previous
//
#include <hip/hip_runtime.h>
#include <math.h>

// ---------------- workspace offsets (bytes) ----------------
#define OFF_CENT   0x0        // int [2][2048]
#define OFF_XSP    0x20000    // float4 [2][2048]
#define OFF_XS6    0x40000    // float [2][2048][6]
#define OFF_KNN    0x60000    // int [2][2048][64] max
#define OFF_F      0x180000   // float [2*2048][512] max
#define OFF_UV     0xA00000   // float [2*2048][1024] max
#define OFF_G      0x1A00000  // float [2*2048][512] max
#define OFF_WCAT   0x2200000  // float [256][1024] max
#define OFF_BCAT   0x2400000  // float [1024]
#define OFF_FUSED  0x2500000  // float [2][4096][1280]  -> ws end 77 MB
#define OFF_T      0x180000   // reuse (post-encoder)
#define OFF_H1     0x1200000  // reuse
#define OFF_T2     0x2200000  // reuse

// ---------------- helpers ----------------
__device__ __forceinline__ unsigned fkey_flip(float f) {
  unsigned u = __float_as_uint(f);
  return u ^ ((u >> 31) ? 0xFFFFFFFFu : 0x80000000u);
}
__device__ __forceinline__ float fkey_unflip(unsigned k) {
  unsigned u = k ^ ((k >> 31) ? 0x80000000u : 0xFFFFFFFFu);
  return __uint_as_float(u);
}

template<int CTRL>
__device__ __forceinline__ float dpp_max_stepf(float v) {
  int t = __builtin_amdgcn_update_dpp(__float_as_int(v), __float_as_int(v),
                                      CTRL, 0xf, 0xf, false);
  return fmaxf(v, __int_as_float(t));
}
__device__ __forceinline__ float wave64_max(float v) {
  v = dpp_max_stepf<0x111>(v);  // row_shr:1
  v = dpp_max_stepf<0x112>(v);  // row_shr:2
  v = dpp_max_stepf<0x114>(v);  // row_shr:4
  v = dpp_max_stepf<0x118>(v);  // row_shr:8
  v = dpp_max_stepf<0x142>(v);  // row_bcast:15
  v = dpp_max_stepf<0x143>(v);  // row_bcast:31
  return __int_as_float(__builtin_amdgcn_readlane(__float_as_int(v), 63));
}
__device__ __forceinline__ unsigned long long u64max(unsigned long long a,
                                                    unsigned long long b) {
  return a > b ? a : b;
}

// ---------------- FPS: one block per batch, sequential 2048 steps ----------------
// 512 threads (8 waves, 2/SIMD for DPP latency overlap). Per wave: f32 DPP max,
// then ballot-based tie-break (8 independent ballots + SALU select, no second
// DPP chain). One barrier/iter; double-buffered 8-slot u64 exchange.
// Distances >= 0 so raw fp32 bits compare like values; ~idx gives ties->lowest.
__global__ __launch_bounds__(512) void fps_kernel(const float* __restrict__ x,
                                                  int* __restrict__ cent)
{
  int b = blockIdx.x, tid = threadIdx.x;
  __shared__ float4 C4[4096];
  __shared__ __align__(16) unsigned long long slots[2][8];
  float px[8], py[8], pz[8], dist[8];
#pragma unroll
  for (int i = 0; i < 8; ++i) {
    int p = tid + 512 * i;
    const float* r = x + ((long)b * 4096 + p) * 6;
    px[i] = r[0]; py[i] = r[1]; pz[i] = r[2];
    C4[p] = make_float4(px[i], py[i], pz[i], 0.0f);
    dist[i] = 1e10f;
  }
  if (tid == 0) cent[b * 2048] = 0;
  __syncthreads();
  float4 c0 = C4[0];
  float cx = c0.x, cy = c0.y, cz = c0.z;
  int wid = tid >> 6, lane = tid & 63;
  for (int j = 1; j < 2048; ++j) {
    float m = -1.0f;
#pragma unroll
    for (int i = 0; i < 8; ++i) {
      // exact replica of sum((xyz-c)**2, -1): ((dx*dx+dy*dy)+dz*dz), no FMA
      float dx = __fsub_rn(px[i], cx);
      float dy = __fsub_rn(py[i], cy);
      float dz = __fsub_rn(pz[i], cz);
      float d  = __fadd_rn(__fadd_rn(__fmul_rn(dx,dx), __fmul_rn(dy,dy)), __fmul_rn(dz,dz));
      float nd = fminf(dist[i], d);
      dist[i] = nd;
      m = fmaxf(m, nd);
    }
    float wm = wave64_max(m);
    // tie-break: lowest i (global idx is i-major), then lowest lane.
    unsigned long long mm = 0ULL; unsigned ii = 0;
#pragma unroll
    for (int i = 7; i >= 0; --i) {        // descending: lowest nonzero i wins last
      unsigned long long mi = __ballot(dist[i] == wm);
      if (mi) { mm = mi; ii = (unsigned)i; }
    }
    int lane_w = __ffsll((unsigned long long)mm) - 1;  // mm != 0 within this wave
    unsigned idx_w = (unsigned)(wid * 64 + lane_w) + 512u * ii;
    if (lane == 0)
      slots[j & 1][wid] = ((unsigned long long)__float_as_uint(wm) << 32)
                        | (unsigned)(0xFFFFFFFFu - idx_w);
    __syncthreads();                      // the only barrier per iteration
    const unsigned long long* sl = slots[j & 1];
    ulonglong2 sA = *(const ulonglong2*)&sl[0];
    ulonglong2 sB = *(const ulonglong2*)&sl[2];
    ulonglong2 sC = *(const ulonglong2*)&sl[4];
    ulonglong2 sD = *(const ulonglong2*)&sl[6];
    unsigned long long kk = u64max(u64max(u64max(sA.x, sA.y), u64max(sB.x, sB.y)),
                                   u64max(u64max(sC.x, sC.y), u64max(sD.x, sD.y)));
    unsigned idx = 0xFFFFFFFFu - (unsigned)kk;
    float4 c = C4[idx];
    cx = c.x; cy = c.y; cz = c.z;
    if (tid == 0) cent[b * 2048 + j] = idx;
  }
}

// ---------------- gather subsampled points ----------------
__global__ void gather_xs_kernel(const float* __restrict__ x, const int* __restrict__ cent,
                                 float* __restrict__ xs6, float4* __restrict__ xsp)
{
  int t = blockIdx.x * 256 + threadIdx.x;
  if (t >= 2 * 2048) return;
  int b = t >> 11;
  int p = cent[t];
  const float* src = x + ((long)b * 4096 + p) * 6;
  float* dst = xs6 + (long)t * 6;
#pragma unroll
  for (int c = 0; c < 6; ++c) dst[c] = src[c];
  xsp[t] = make_float4(src[0], src[1], src[2], 0.0f);
}

// ---------------- kNN: one wave per query ----------------
template<int S, int K>
__global__ __launch_bounds__(256) void knn_kernel(const float4* __restrict__ xsp,
                                                  int* __restrict__ out)
{
  constexpr int NI = S / 64;
  __shared__ float4 P[S];
  int b = (blockIdx.x * 4) / S;
  int wid = threadIdx.x >> 6, lane = threadIdx.x & 63;
  int s = (blockIdx.x * 4 + wid) & (S - 1);
  for (int i = threadIdx.x; i < S; i += 256) P[i] = xsp[b * 2048 + i];
  __syncthreads();
  float4 Q = P[s];
  float saq = __fadd_rn(__fadd_rn(__fmul_rn(Q.x,Q.x), __fmul_rn(Q.y,Q.y)), __fmul_rn(Q.z,Q.z));
  float dd[NI];
#pragma unroll
  for (int i = 0; i < NI; ++i) {
    float4 c = P[i * 64 + lane];
    float sac = __fadd_rn(__fadd_rn(__fmul_rn(c.x,c.x), __fmul_rn(c.y,c.y)), __fmul_rn(c.z,c.z));
    float dot = __fadd_rn(__fadd_rn(__fmul_rn(Q.x,c.x), __fmul_rn(Q.y,c.y)), __fmul_rn(Q.z,c.z));
    dd[i] = __fsub_rn(__fadd_rn(saq, sac), __fmul_rn(2.0f, dot));
  }
  long obase = ((long)b * S + s) * K;
  for (int t = 0; t < K; ++t) {
    float bv = INFINITY; int bi = 0;
#pragma unroll
    for (int i = 0; i < NI; ++i) if (dd[i] < bv) { bv = dd[i]; bi = i; }
    unsigned long long key = ((unsigned long long)fkey_flip(bv) << 32)
                           | (unsigned)(bi * 64 + lane);
#pragma unroll
    for (int m = 32; m; m >>= 1) {
      unsigned long long o = __shfl_xor(key, m, 64);
      if (o < key) key = o;
    }
    unsigned cand = (unsigned)key;
    if ((int)(cand & 63) == lane) {
      int slot = cand >> 6;
#pragma unroll
      for (int i = 0; i < NI; ++i) if (i == slot) dd[i] = INFINITY;
    }
    if (lane == 0) out[obase + t] = (int)cand;
  }
}

// ---------------- Wcat prep: [2C,C'] -> [C, 2C'] with (Wa-Wb | Wb), bias -> (b | 0) ----------------
__global__ void wcat_prep(const float* __restrict__ W, const float* __restrict__ bias,
                          int C, int Cp, float* __restrict__ Wcat, float* __restrict__ bcat)
{
  int n2 = 2 * Cp;
  int total = C * n2;
  for (int t = blockIdx.x * 256 + threadIdx.x; t < total + n2; t += gridDim.x * 256) {
    if (t < total) {
      int c = t / n2, n = t % n2;
      Wcat[t] = (n < Cp) ? (W[c * Cp + n] - W[(C + c) * Cp + n]) : W[(C + c) * Cp + (n - Cp)];
    } else {
      int n = t - total;
      bcat[n] = (n < Cp) ? bias[n] : 0.0f;
    }
  }
}

// ---------------- generic fp32 GEMM: C = A[M,K] * W[K,N] + bias (64x64 tile) ----------------
__global__ __launch_bounds__(256) void gemm_bias(
    const float* __restrict__ A, long strideA, int lda,
    const float* __restrict__ W, int N, int K,
    const float* __restrict__ bias,
    float* __restrict__ C, long strideC, int ldc)
{
  A += (long)blockIdx.z * strideA;
  C += (long)blockIdx.z * strideC;
  int rowBase = blockIdx.x * 64, colBase = blockIdx.y * 64;
  __shared__ float As[16][68];
  __shared__ float Ws[16][68];
  int tid = threadIdx.x;
  int tx = tid & 15, ty = tid >> 4;
  float acc[4][4] = {};
  for (int k0 = 0; k0 < K; k0 += 16) {
    {
      int r = tid >> 2, c0 = (tid & 3) * 4;
      const float* Ar = A + (long)(rowBase + r) * lda + k0 + c0;
#pragma unroll
      for (int u = 0; u < 4; ++u) {
        float val = 0.0f;
        if (k0 + c0 + u < K) val = Ar[u];
        As[c0 + u][r] = val;
      }
    }
    {
      int c = tid & 63, kr = tid >> 6;
#pragma unroll
      for (int u = 0; u < 4; ++u) {
        int kk = kr + u * 4;
        float val = 0.0f;
        if (k0 + kk < K) val = W[(long)(k0 + kk) * N + colBase + c];
        Ws[kk][c] = val;
      }
    }
    __syncthreads();
#pragma unroll
    for (int kk = 0; kk < 16; ++kk) {
      float4 av = *(const float4*)&As[kk][ty * 4];
      float4 wv = *(const float4*)&Ws[kk][tx * 4];
      float a_[4] = {av.x, av.y, av.z, av.w};
      float w_[4] = {wv.x, wv.y, wv.z, wv.w};
#pragma unroll
      for (int i = 0; i < 4; ++i)
#pragma unroll
        for (int j = 0; j < 4; ++j)
          acc[i][j] = fmaf(a_[i], w_[j], acc[i][j]);
    }
    __syncthreads();
  }
#pragma unroll
  for (int i = 0; i < 4; ++i) {
    int r = rowBase + ty * 4 + i;
    int c0 = colBase + tx * 4;
    float4 o;
    o.x = acc[i][0] + bias[c0 + 0];
    o.y = acc[i][1] + bias[c0 + 1];
    o.z = acc[i][2] + bias[c0 + 2];
    o.w = acc[i][3] + bias[c0 + 3];
    *(float4*)&C[(long)r * ldc + c0] = o;
  }
}

// ---------------- big fp32 GEMM: 128x128 tile, 8x8 acc/thread ----------------
// Requires M%128==0, N%128==0, K%16==0. Same k-ascending fmaf order as gemm_bias.
__global__ __launch_bounds__(256) void gemm_bias_big(
    const float* __restrict__ A, int lda,
    const float* __restrict__ W, int N, int K,
    const float* __restrict__ bias,
    float* __restrict__ C, int ldc)
{
  int rowBase = blockIdx.x * 128, colBase = blockIdx.y * 128;
  __shared__ float As[16][132];
  __shared__ float Ws[16][132];
  int tid = threadIdx.x;
  int tx = tid & 15, ty = tid >> 4;
  float acc[8][8] = {};
  for (int k0 = 0; k0 < K; k0 += 16) {
    {
      int r = tid >> 1, c0 = (tid & 1) * 8;
      const float* Ar = A + (long)(rowBase + r) * lda + k0 + c0;
      float4 v0 = *(const float4*)(Ar);
      float4 v1 = *(const float4*)(Ar + 4);
      As[c0 + 0][r] = v0.x; As[c0 + 1][r] = v0.y; As[c0 + 2][r] = v0.z; As[c0 + 3][r] = v0.w;
      As[c0 + 4][r] = v1.x; As[c0 + 5][r] = v1.y; As[c0 + 6][r] = v1.z; As[c0 + 7][r] = v1.w;
    }
    {
      int kr = tid >> 4, c0 = (tid & 15) * 8;
      const float* Wr = W + (long)(k0 + kr) * N + colBase + c0;
      float4 w0 = *(const float4*)(Wr);
      float4 w1 = *(const float4*)(Wr + 4);
      *(float4*)&Ws[kr][c0]     = w0;
      *(float4*)&Ws[kr][c0 + 4] = w1;
    }
    __syncthreads();
#pragma unroll
    for (int kk = 0; kk < 16; ++kk) {
      float a_[8], w_[8];
      *(float4*)&a_[0] = *(const float4*)&As[kk][ty * 8];
      *(float4*)&a_[4] = *(const float4*)&As[kk][ty * 8 + 4];
      *(float4*)&w_[0] = *(const float4*)&Ws[kk][tx * 8];
      *(float4*)&w_[4] = *(const float4*)&Ws[kk][tx * 8 + 4];
#pragma unroll
      for (int i = 0; i < 8; ++i)
#pragma unroll
        for (int jj = 0; jj < 8; ++jj)
          acc[i][jj] = fmaf(a_[i], w_[jj], acc[i][jj]);
    }
    __syncthreads();
  }
#pragma unroll
  for (int i = 0; i < 8; ++i) {
    int r = rowBase + ty * 8 + i;
    int c0 = colBase + tx * 8;
    float4 o0, o1;
    o0.x = acc[i][0] + bias[c0 + 0];
    o0.y = acc[i][1] + bias[c0 + 1];
    o0.z = acc[i][2] + bias[c0 + 2];
    o0.w = acc[i][3] + bias[c0 + 3];
    o1.x = acc[i][4] + bias[c0 + 4];
    o1.y = acc[i][5] + bias[c0 + 5];
    o1.z = acc[i][6] + bias[c0 + 6];
    o1.w = acc[i][7] + bias[c0 + 7];
    *(float4*)&C[(long)r * ldc + c0]     = o0;
    *(float4*)&C[(long)r * ldc + c0 + 4] = o1;
  }
}

// ---------------- edge aggregation: F[s] = relu(u[s] + max_j v[nbr_j]) ----------------
__global__ void edge_agg(const float* __restrict__ UV, const int* __restrict__ idx,
                         int S, int k, int Cp, float* __restrict__ F)
{
  int bs = blockIdx.x;
  int b = bs / S;
  __shared__ int nb[64];
  if ((int)threadIdx.x < k) nb[threadIdx.x] = idx[(long)bs * k + threadIdx.x];
  __syncthreads();
  int ld = 2 * Cp;
  const float* Ub = UV + (long)bs * ld;
  for (int c = threadIdx.x; c < Cp; c += blockDim.x) {
    float m = -INFINITY;
    for (int j = 0; j < k; ++j) {
      float v = UV[(long)(b * S + nb[j]) * ld + Cp + c];
      m = fmaxf(m, v);
    }
    float r = Ub[c] + m;
    F[(long)bs * Cp + c] = r > 0.0f ? r : 0.0f;
  }
}

// ---------------- upsample: 3-NN inverse-distance interp, writes into fused concat ----------------
template<int S, int CP>
__global__ __launch_bounds__(256) void upsample_kernel(
    const float* __restrict__ x, const float4* __restrict__ xsp,
    const float* __restrict__ G, float* __restrict__ fused, int colOff)
{
  constexpr int NI = S / 64;
  __shared__ float4 P[S];
  int b = (blockIdx.x * 4) >> 12;
  int wid = threadIdx.x >> 6, lane = threadIdx.x & 63;
  int n = (blockIdx.x * 4 + wid) & 4095;
  for (int i = threadIdx.x; i < S; i += 256) P[i] = xsp[b * 2048 + i];
  __syncthreads();
  const float* q = x + ((long)b * 4096 + n) * 6;
  float qx = q[0], qy = q[1], qz = q[2];
  float saq = __fadd_rn(__fadd_rn(__fmul_rn(qx,qx), __fmul_rn(qy,qy)), __fmul_rn(qz,qz));
  float dd[NI];
#pragma unroll
  for (int i = 0; i < NI; ++i) {
    float4 c = P[i * 64 + lane];
    float sac = __fadd_rn(__fadd_rn(__fmul_rn(c.x,c.x), __fmul_rn(c.y,c.y)), __fmul_rn(c.z,c.z));
    float dot = __fadd_rn(__fadd_rn(__fmul_rn(qx,c.x), __fmul_rn(qy,c.y)), __fmul_rn(qz,c.z));
    dd[i] = __fsub_rn(__fadd_rn(saq, sac), __fmul_rn(2.0f, dot));
  }
  int id[3]; float w[3];
  for (int t = 0; t < 3; ++t) {
    float bv = INFINITY; int bi = 0;
#pragma unroll
    for (int i = 0; i < NI; ++i) if (dd[i] < bv) { bv = dd[i]; bi = i; }
    unsigned long long key = ((unsigned long long)fkey_flip(bv) << 32)
                           | (unsigned)(bi * 64 + lane);
#pragma unroll
    for (int m = 32; m; m >>= 1) {
      unsigned long long o = __shfl_xor(key, m, 64);
      if (o < key) key = o;
    }
    unsigned cand = (unsigned)key;
    float d2 = fkey_unflip((unsigned)(key >> 32));
    float d = __fsqrt_rn(fmaxf(d2, 0.0f));
    id[t] = (int)cand;
    w[t] = 1.0f / __fadd_rn(d, 1e-8f);
    if ((int)(cand & 63) == lane) {
      int slot = cand >> 6;
#pragma unroll
      for (int i = 0; i < NI; ++i) if (i == slot) dd[i] = INFINITY;
    }
  }
  float wsum = __fadd_rn(__fadd_rn(w[0], w[1]), w[2]);
  float w0 = w[0] / wsum, w1 = w[1] / wsum, w2 = w[2] / wsum;
  const float* g0 = G + (long)(b * S + id[0]) * CP;
  const float* g1 = G + (long)(b * S + id[1]) * CP;
  const float* g2 = G + (long)(b * S + id[2]) * CP;
  float* orow = fused + ((long)b * 4096 + n) * 1280 + colOff;
#pragma unroll
  for (int t = 0; t < CP / 64; ++t) {
    int c = lane + 64 * t;
    float v = __fadd_rn(__fadd_rn(__fmul_rn(w0, g0[c]), __fmul_rn(w1, g1[c])),
                        __fmul_rn(w2, g2[c]));
    orow[c] = v;
  }
}

// ---------------- GroupNorm(32,512) + relu (+ optional pos-enc), one group per thread ----------------
__global__ __launch_bounds__(256) void gn_kernel(const float* __restrict__ T,
    const float* __restrict__ gw, const float* __restrict__ gb,
    float* __restrict__ out, int addPos)
{
  int t = blockIdx.x * 256 + threadIdx.x;
  int row = t >> 5, g = t & 31;
  const float* p = T + (long)row * 512 + g * 16;
  float v[16];
#pragma unroll
  for (int i = 0; i < 4; ++i) {
    float4 f = *(const float4*)(p + i * 4);
    v[i*4+0] = f.x; v[i*4+1] = f.y; v[i*4+2] = f.z; v[i*4+3] = f.w;
  }
  float s = 0.0f;
#pragma unroll
  for (int i = 0; i < 16; ++i) s += v[i];
  float mu = s * 0.0625f;
  float var = 0.0f;
#pragma unroll
  for (int i = 0; i < 16; ++i) { float d = v[i] - mu; var += d * d; }
  var *= 0.0625f;
  float inv = 1.0f / sqrtf(var + 1e-5f);
  int cbase = g * 16;
  int n = row & 4095;
  float o[16];
#pragma unroll
  for (int i = 0; i < 16; ++i) {
    int c = cbase + i;
    float y = (v[i] - mu) * inv * gw[c] + gb[c];
    y = y > 0.0f ? y : 0.0f;
    if (addPos) {
      int half = c >> 1;
      float div = expf((float)(2 * half) * -0.017988946039016358f); // -ln(10000)/512
      float ang = (float)n * div;
      y += (c & 1) ? cosf(ang) : sinf(ang);
    }
    o[i] = y;
  }
  float* d = out + (long)row * 512 + cbase;
#pragma unroll
  for (int i = 0; i < 4; ++i) {
    float4 f; f.x = o[i*4+0]; f.y = o[i*4+1]; f.z = o[i*4+2]; f.w = o[i*4+3];
    *(float4*)(d + i * 4) = f;
  }
}

// ---------------- host-side launch helpers ----------------
static inline void launch_gemm(const float* A, long strideA, int lda,
                               const float* W, const float* bias,
                               float* C, long strideC, int ldc,
                               int Mb, int N, int K, int nb, hipStream_t s)
{
  dim3 grid(Mb / 64, N / 64, nb);
  gemm_bias<<<grid, 256, 0, s>>>(A, strideA, lda, W, N, K, bias, C, strideC, ldc);
}
static inline void launch_gemm_big(const float* A, int lda,
                                   const float* W, const float* bias,
                                   float* C, int ldc,
                                   int M, int N, int K, hipStream_t s)
{
  dim3 grid(M / 128, N / 128, 1);
  gemm_bias_big<<<grid, 256, 0, s>>>(A, lda, W, N, K, bias, C, ldc);
}

extern "C" void kernel_launch(void* const* d_in, const int* in_sizes, int n_in,
                              void* d_out, int out_size, void* d_ws, size_t ws_size,
                              hipStream_t stream)
{
  const float* x     = (const float*)d_in[0];
  const float* e1_W0 = (const float*)d_in[1];  const float* e1_b0 = (const float*)d_in[2];
  const float* e1_W1 = (const float*)d_in[3];  const float* e1_b1 = (const float*)d_in[4];
  const float* e1_Wo = (const float*)d_in[5];  const float* e1_bo = (const float*)d_in[6];
  const float* e2_W0 = (const float*)d_in[7];  const float* e2_b0 = (const float*)d_in[8];
  const float* e2_W1 = (const float*)d_in[9];  const float* e2_b1 = (const float*)d_in[10];
  const float* e2_Wo = (const float*)d_in[11]; const float* e2_bo = (const float*)d_in[12];
  const float* e3_W0 = (const float*)d_in[13]; const float* e3_b0 = (const float*)d_in[14];
  const float* e3_W1 = (const float*)d_in[15]; const float* e3_b1 = (const float*)d_in[16];
  const float* e3_W2 = (const float*)d_in[17]; const float* e3_b2 = (const float*)d_in[18];
  const float* e3_Wo = (const float*)d_in[19]; const float* e3_bo = (const float*)d_in[20];
  const float* f_W1  = (const float*)d_in[21]; const float* f_b1  = (const float*)d_in[22];
  const float* g1_w  = (const float*)d_in[23]; const float* g1_b  = (const float*)d_in[24];
  const float* f_W2  = (const float*)d_in[25]; const float* f_b2  = (const float*)d_in[26];
  const float* g2_w  = (const float*)d_in[27]; const float* g2_b  = (const float*)d_in[28];

  char* ws = (char*)d_ws;
  int*    cent  = (int*)(ws + OFF_CENT);
  float4* xsp   = (float4*)(ws + OFF_XSP);
  float*  xs6   = (float*)(ws + OFF_XS6);
  int*    knn   = (int*)(ws + OFF_KNN);
  float*  F     = (float*)(ws + OFF_F);
  float*  UV    = (float*)(ws + OFF_UV);
  float*  G     = (float*)(ws + OFF_G);
  float*  WCAT  = (float*)(ws + OFF_WCAT);
  float*  BCAT  = (float*)(ws + OFF_BCAT);
  float*  FUSED = (float*)(ws + OFF_FUSED);
  float*  T     = (float*)(ws + OFF_T);
  float*  H1    = (float*)(ws + OFF_H1);
  float*  T2    = (float*)(ws + OFF_T2);

  fps_kernel<<<2, 512, 0, stream>>>(x, cent);
  gather_xs_kernel<<<16, 256, 0, stream>>>(x, cent, xs6, xsp);

  // ---- encoder 1: S=512, k=16, 6->128->256, proj 256 ----
  knn_kernel<512,16><<<256, 256, 0, stream>>>(xsp, knn);
  wcat_prep<<<256, 256, 0, stream>>>(e1_W0, e1_b0, 6, 128, WCAT, BCAT);
  launch_gemm(xs6, (long)2048*6, 6, WCAT, BCAT, UV, (long)512*256, 256, 512, 256, 6, 2, stream);
  edge_agg<<<dim3(2*512), 128, 0, stream>>>(UV, knn, 512, 16, 128, F);
  wcat_prep<<<256, 256, 0, stream>>>(e1_W1, e1_b1, 128, 256, WCAT, BCAT);
  launch_gemm(F, 0, 128, WCAT, BCAT, UV, 0, 512, 1024, 512, 128, 1, stream);
  edge_agg<<<dim3(2*512), 256, 0, stream>>>(UV, knn, 512, 16, 256, F);
  launch_gemm(F, 0, 256, e1_Wo, e1_bo, G, 0, 256, 1024, 256, 256, 1, stream);
  upsample_kernel<512,256><<<2048, 256, 0, stream>>>(x, xsp, G, FUSED, 0);

  // ---- encoder 2: S=1024, k=32, 6->256->512, proj 512 ----
  knn_kernel<1024,32><<<512, 256, 0, stream>>>(xsp, knn);
  wcat_prep<<<256, 256, 0, stream>>>(e2_W0, e2_b0, 6, 256, WCAT, BCAT);
  launch_gemm(xs6, (long)2048*6, 6, WCAT, BCAT, UV, (long)1024*512, 512, 1024, 512, 6, 2, stream);
  edge_agg<<<dim3(2*1024), 256, 0, stream>>>(UV, knn, 1024, 32, 256, F);
  wcat_prep<<<256, 256, 0, stream>>>(e2_W1, e2_b1, 256, 512, WCAT, BCAT);
  launch_gemm_big(F, 256, WCAT, BCAT, UV, 1024, 2048, 1024, 256, stream);
  edge_agg<<<dim3(2*1024), 256, 0, stream>>>(UV, knn, 1024, 32, 512, F);
  launch_gemm(F, 0, 512, e2_Wo, e2_bo, G, 0, 512, 2048, 512, 512, 1, stream);
  upsample_kernel<1024,512><<<2048, 256, 0, stream>>>(x, xsp, G, FUSED, 256);

  // ---- encoder 3: S=2048, k=64, 6->128->256->512, proj 512 ----
  knn_kernel<2048,64><<<1024, 256, 0, stream>>>(xsp, knn);
  wcat_prep<<<256, 256, 0, stream>>>(e3_W0, e3_b0, 6, 128, WCAT, BCAT);
  launch_gemm(xs6, (long)2048*6, 6, WCAT, BCAT, UV, (long)2048*256, 256, 2048, 256, 6, 2, stream);
  edge_agg<<<dim3(2*2048), 128, 0, stream>>>(UV, knn, 2048, 64, 128, F);
  wcat_prep<<<256, 256, 0, stream>>>(e3_W1, e3_b1, 128, 256, WCAT, BCAT);
  launch_gemm_big(F, 128, WCAT, BCAT, UV, 512, 4096, 512, 128, stream);
  edge_agg<<<dim3(2*2048), 256, 0, stream>>>(UV, knn, 2048, 64, 256, F);
  wcat_prep<<<256, 256, 0, stream>>>(e3_W2, e3_b2, 256, 512, WCAT, BCAT);
  launch_gemm_big(F, 256, WCAT, BCAT, UV, 1024, 4096, 1024, 256, stream);
  edge_agg<<<dim3(2*2048), 256, 0, stream>>>(UV, knn, 2048, 64, 512, F);
  launch_gemm_big(F, 512, e3_Wo, e3_bo, G, 512, 4096, 512, 512, stream);
  upsample_kernel<2048,512><<<2048, 256, 0, stream>>>(x, xsp, G, FUSED, 768);

  // ---- fusion MLP + GroupNorm + pos-enc ----
  launch_gemm_big(FUSED, 1280, f_W1, f_b1, T, 512, 8192, 512, 1280, stream);
  gn_kernel<<<1024, 256, 0, stream>>>(T, g1_w, g1_b, H1, 0);
  launch_gemm_big(H1, 512, f_W2, f_b2, T2, 512, 8192, 512, 512, stream);
  gn_kernel<<<1024, 256, 0, stream>>>(T2, g2_w, g2_b, (float*)d_out, 1);
}